// Round 3
// baseline (8549.008 us; speedup 1.0000x reference)
//
#include <hip/hip_runtime.h>
#include <math.h>

typedef __bf16 bf16_t;
typedef __bf16 bfrag  __attribute__((ext_vector_type(8)));  // 8 bf16 (MFMA A/B frag)
typedef __bf16 b4     __attribute__((ext_vector_type(4)));  // 4 bf16 = 8B vector store
typedef __bf16 b2v    __attribute__((ext_vector_type(2)));  // 2 bf16 = 4B vector
typedef float  f32x4  __attribute__((ext_vector_type(4)));  // MFMA C/D frag

static constexpr int LY  = 5;
static constexpr int H   = 256;
static constexpr int NN  = 200000;
static constexpr int EE  = 400000;
static constexpr int GG  = 8000;
static constexpr int NPG = 25;
static constexpr int CAP = 24;   // max buffered in-edges/node (Poisson(2): P(>24) ~ 1e-17)
static constexpr int NBLK_NODE = NN / 32;   // 6250
static constexpr int NBLK_VN   = GG / 32;   // 250

// tanh-approx GELU (~8 VALU ops; |delta| vs exact erf-gelu ~3e-4 absolute)
__device__ __forceinline__ float gelu_f(float x) {
    const float y = 0.7978845608028654f * x * (1.0f + 0.044715f * x * x);
    const float e = __expf(2.0f * y);
    const float t = 1.0f - 2.0f / (e + 1.0f);
    return 0.5f * x * (1.0f + t);
}

// ---------------- diagnostics ----------------
__global__ void k_fill(float* __restrict__ out, float v, int n) {
    const int i = blockIdx.x * 256 + threadIdx.x;
    if (i < n) out[i] = v;
}

// ---------------- dtype detection ----------------
__global__ void k_detect(const void* __restrict__ probe, int* __restrict__ flag) {
    const bf16_t* p = (const bf16_t*)probe;
    int bad = 0;
    for (int i = threadIdx.x; i < 256; i += 64) {
        const float v = (float)p[i];
        if (!(v == v) || fabsf(v) > 1000.0f) bad = 1;
    }
    const int any = __any(bad) ? 1 : 0;
    if (threadIdx.x == 0) *flag = any;
}

// ---------------- batched param conversion (1 launch) ----------------
struct CvtJobs {
    const void* src[18];
    bf16_t*     dst[18];
    int         pfx[19];
    int         njobs;
};
__global__ void k_cvt_all(CvtJobs J, const int* __restrict__ flag) {
    const int i = blockIdx.x * 256 + threadIdx.x;
    if (i >= J.pfx[J.njobs]) return;
    int j = 0;
    while (i >= J.pfx[j + 1]) ++j;
    const int loc = i - J.pfx[j];
    if (*flag) J.dst[j][loc] = (bf16_t)((const float*)J.src[j])[loc];
    else       J.dst[j][loc] = ((const bf16_t*)J.src[j])[loc];
}

// ---------------- batched weight transpose (1 launch) ----------------
struct TpJobs {
    const void* s32[22];
    const void* s16[22];
    bf16_t*     dst[22];
    int R[22], C[22];
    int pfx[23];
    int njobs;
};
__global__ void k_tp_all(TpJobs J, const int* __restrict__ flag) {
    __shared__ bf16_t t[32][33];
    const int tile = blockIdx.x;
    int j = 0;
    while (tile >= J.pfx[j + 1]) ++j;
    const int tl = tile - J.pfx[j];
    const int C = J.C[j], R = J.R[j];
    const int ntx = C / 32;
    const int c0 = (tl % ntx) * 32, r0 = (tl / ntx) * 32;
    const int f = *flag;
    const int tx = threadIdx.x & 31, ty = threadIdx.x >> 5;
    #pragma unroll
    for (int i = 0; i < 4; ++i) {
        const int r = ty + i * 8;
        const size_t idx = (size_t)(r0 + r) * C + c0 + tx;
        t[r][tx] = f ? (bf16_t)((const float*)J.s32[j])[idx] : ((const bf16_t*)J.s16[j])[idx];
    }
    __syncthreads();
    #pragma unroll
    for (int i = 0; i < 4; ++i) {
        const int r = ty + i * 8;
        J.dst[j][(size_t)(c0 + r) * R + r0 + tx] = t[tx][r];
    }
}

// ---------------- init ----------------
__global__ void k_init_h(const int* __restrict__ x, const bf16_t* __restrict__ atom,
                         bf16_t* __restrict__ h) {
    const size_t idx = (size_t)blockIdx.x * 256 + threadIdx.x;
    const int row = (int)(idx >> 8), col = (int)(idx & 255);
    h[idx] = atom[(size_t)x[row] * H + col];
}

__global__ void k_init_vn(const bf16_t* __restrict__ vne, float* __restrict__ vn) {
    const size_t idx = (size_t)blockIdx.x * 256 + threadIdx.x;
    vn[idx] = (float)vne[idx & 255];
}

// ---------------- edge bucket build (packed src|attr slots) ----------------
__global__ void k_zero_cnt(int* __restrict__ cnt) {
    const int i = blockIdx.x * 256 + threadIdx.x;
    if (i < NN) cnt[i] = 0;
}

// slots hold src | (attr << 18)  (src < 2^18 since NN=200000 < 262144; attr < 8)
__global__ void k_bucket(const int* __restrict__ ei, const int* __restrict__ ea,
                         int* __restrict__ cnt, int* __restrict__ slots) {
    const int e = blockIdx.x * 256 + threadIdx.x;
    if (e >= EE) return;
    const int d = ei[EE + e];
    const int s = ei[e];
    const int a = ea[e];
    const int slot = atomicAdd(&cnt[d], 1);
    if (slot < CAP) slots[(size_t)d * CAP + slot] = s | (a << 18);
}

// ---------------- fused addvn + segment_max (block = 1 graph, bf16x2 lanes) ----------------
__global__ void k_addvn_segmax(bf16_t* __restrict__ h, const float* __restrict__ vn,
                               bf16_t* __restrict__ vp, int do_max) {
    const int g = blockIdx.x, t = threadIdx.x;   // 128 threads; cols 2t, 2t+1
    const float2 v = *(const float2*)(vn + (size_t)g * H + 2 * t);
    float mx0 = -1e30f, mx1 = -1e30f;
    #pragma unroll 5
    for (int i = 0; i < NPG; ++i) {
        bf16_t* p = h + ((size_t)g * NPG + i) * H + 2 * t;
        const b2v hv = *(const b2v*)p;
        const float h0 = (float)hv[0] + v.x;
        const float h1 = (float)hv[1] + v.y;
        b2v o; o[0] = (bf16_t)h0; o[1] = (bf16_t)h1;
        *(b2v*)p = o;
        mx0 = fmaxf(mx0, h0); mx1 = fmaxf(mx1, h1);
    }
    if (do_max) {
        b2v o; o[0] = (bf16_t)mx0; o[1] = (bf16_t)mx1;
        *(b2v*)(vp + (size_t)g * H + 2 * t) = o;
    }
}

// ---------------- edge gather (bf16x2 lanes; packed slots: 2-level chain) ----------------
__global__ void k_gather(const bf16_t* __restrict__ h,
                         const bf16_t* __restrict__ bondl,
                         const int* __restrict__ cnt, const int* __restrict__ slots,
                         const bf16_t* __restrict__ epsb, int l, bf16_t* __restrict__ Xb) {
    const int n = blockIdx.x, t = threadIdx.x;   // 128 threads; cols 2t, 2t+1
    int deg = cnt[n];
    if (deg > CAP) deg = CAP;
    float m0 = 0.0f, m1 = 0.0f;
    for (int i = 0; i < deg; ++i) {
        const int p = slots[(size_t)n * CAP + i];
        const int s = p & 0x3FFFF;
        const int a = p >> 18;
        const b2v hv = *(const b2v*)(h + (size_t)s * H + 2 * t);
        const b2v bv = *(const b2v*)(bondl + (size_t)a * H + 2 * t);
        m0 += gelu_f((float)hv[0] + (float)bv[0]);
        m1 += gelu_f((float)hv[1] + (float)bv[1]);
    }
    const float eps1 = 1.0f + (float)epsb[l];
    const b2v hn = *(const b2v*)(h + (size_t)n * H + 2 * t);
    b2v o;
    o[0] = (bf16_t)(eps1 * (float)hn[0] + m0);
    o[1] = (bf16_t)(eps1 * (float)hn[1] + m1);
    *(b2v*)(Xb + (size_t)n * H + 2 * t) = o;
}

__global__ void k_graphsum(const bf16_t* __restrict__ h, bf16_t* __restrict__ hg) {
    const int g = blockIdx.x, t = threadIdx.x;   // 128 threads
    float s0 = 0.0f, s1 = 0.0f;
    #pragma unroll 5
    for (int i = 0; i < NPG; ++i) {
        const b2v hv = *(const b2v*)(h + ((size_t)g * NPG + i) * H + 2 * t);
        s0 += (float)hv[0]; s1 += (float)hv[1];
    }
    b2v o; o[0] = (bf16_t)s0; o[1] = (bf16_t)s1;
    *(b2v*)(hg + (size_t)g * H + 2 * t) = o;
}

__global__ void k_norm(const float* __restrict__ z, float* __restrict__ out) {
    const int row = blockIdx.x, t = threadIdx.x;
    const size_t idx = (size_t)row * H + t;
    const float v = z[idx];
    float q = v * v;
    #pragma unroll
    for (int o = 32; o > 0; o >>= 1) q += __shfl_xor(q, o, 64);
    __shared__ float rq[4];
    const int wave = t >> 6, lane = t & 63;
    if (lane == 0) rq[wave] = q;
    __syncthreads();
    q = rq[0] + rq[1] + rq[2] + rq[3];
    out[idx] = v * rsqrtf(q);
}

// ---------------- fused MLP dual: node (LN+res) + vn (accumulate) in ONE dispatch ----------------
// BARRIER-FREE weight staging: each wave stages and consumes ONLY its own 2 KB
// LDS region (16 cols x 32 k = 1 KB per half-round, double-buffered), so the
// 128 block-wide __syncthreads() of the old design synchronized waves sharing
// NOTHING. They are replaced by per-wave counted s_waitcnt vmcnt(N). The
// per-lane global source is pre-swizzled so each lane reads back exactly the
// 16 B it loaded (linear, conflict-free, no XOR). X fragments are software-
// pipelined in registers one round ahead; biases preloaded -> no stray global
// loads inside the loops. Barriers remain only around the LN phases.
// LDS = 64 KB hid + 16 KB wbuf = 80 KB -> 2 blocks/CU, 16 waves/CU.
__launch_bounds__(512, 4)
__global__ void k_mlp_dual(const bf16_t* __restrict__ Xn, const bf16_t* __restrict__ Xv,
                           const bf16_t* __restrict__ nW1T, const bf16_t* __restrict__ vW1T,
                           const bf16_t* __restrict__ nb1, const bf16_t* __restrict__ vb1,
                           const bf16_t* __restrict__ nlng, const bf16_t* __restrict__ vlng,
                           const bf16_t* __restrict__ nlnb, const bf16_t* __restrict__ vlnb,
                           const bf16_t* __restrict__ nW2T, const bf16_t* __restrict__ vW2T,
                           const bf16_t* __restrict__ nb2, const bf16_t* __restrict__ vb2,
                           const bf16_t* __restrict__ g2, const bf16_t* __restrict__ b2ln,
                           bf16_t* __restrict__ hres, float* __restrict__ vnacc,
                           int gelu_flag, int nblk_node, int has_vn) {
    constexpr int HID = 1024;
    __shared__ __align__(16) bf16_t hid[32 * HID];   // 64 KB
    __shared__ __align__(16) bf16_t wbuf[8192];      // 16 KB: 8 waves x 2 halves x 512
    const int tid  = threadIdx.x;
    const int lane = tid & 63, wave = tid >> 6;
    const int c16  = lane & 15, quad = lane >> 4;

    const bool is_node = (int)blockIdx.x < nblk_node;
    const size_t rowblk = is_node ? (size_t)blockIdx.x * 32
                                  : (size_t)((int)blockIdx.x - nblk_node) * 32;
    const bf16_t* X    = is_node ? Xn   : Xv;
    const bf16_t* W1T  = is_node ? nW1T : vW1T;
    const bf16_t* W2T  = is_node ? nW2T : vW2T;
    const bf16_t* b1   = is_node ? nb1  : vb1;
    const bf16_t* lng  = is_node ? nlng : vlng;
    const bf16_t* lnb  = is_node ? nlnb : vlnb;
    const bf16_t* b2   = is_node ? nb2  : vb2;

    // per-wave private LDS slab (2 halves x 512 bf16 = 2 KB)
    bf16_t* wb = wbuf + wave * 1024;
    // per-lane weight bases: lane reads W[col = base + (lane&15)][k = .. + (lane>>4)*8]
    const bf16_t* w1l = W1T + (size_t)(wave * 16 + c16) * 256  + quad * 8;
    const bf16_t* w2l = W2T + (size_t)(wave * 16 + c16) * 1024 + quad * 8;

    auto stage1 = [&](int hr) {   // hr in [0,64): c = hr>>3, ks = hr&7
        const bf16_t* gp = w1l + (size_t)(hr >> 3) * (128 * 256) + (hr & 7) * 32;
        bf16_t* lp = wb + (hr & 1) * 512;
        __builtin_amdgcn_global_load_lds(
            (const __attribute__((address_space(1))) void*)gp,
            (__attribute__((address_space(3))) void*)lp, 16, 0, 0);
    };
    auto stage2 = [&](int g) {    // g in [0,64): cp = g>>5, kt = g&31; half = g&1
        const bf16_t* gp = w2l + (size_t)(g >> 5) * (128 * 1024) + (g & 31) * 32;
        bf16_t* lp = wb + (g & 1) * 512;
        __builtin_amdgcn_global_load_lds(
            (const __attribute__((address_space(1))) void*)gp,
            (__attribute__((address_space(3))) void*)lp, 16, 0, 0);
    };

    // ---- bias preload (keeps loops free of stray global loads) ----
    b4 bias1[8], bias2[2];
    #pragma unroll
    for (int c = 0; c < 8; ++c)
        bias1[c] = *(const b4*)(b1 + c * 128 + wave * 16 + quad * 4);
    #pragma unroll
    for (int cp = 0; cp < 2; ++cp)
        bias2[cp] = *(const b4*)(b2 + cp * 128 + wave * 16 + quad * 4);

    // ---- X fragment pipeline (1-round register lookahead) ----
    const bf16_t* xr0 = X + (rowblk + c16) * 256 + quad * 8;
    const bf16_t* xr1 = X + (rowblk + 16 + c16) * 256 + quad * 8;
    bfrag xb0[2], xb1[2];

    // ---- prologue ----
    stage1(0);
    xb0[0] = *(const bfrag*)(xr0);
    xb1[0] = *(const bfrag*)(xr1);

    // ---- GEMM1: hid[32,1024] = X[32,256] @ W1, barrier-free ----
    #pragma unroll
    for (int c = 0; c < 8; ++c) {
        f32x4 acc0 = f32x4{0.f, 0.f, 0.f, 0.f};
        f32x4 acc1 = f32x4{0.f, 0.f, 0.f, 0.f};
        #pragma unroll
        for (int ks = 0; ks < 8; ++ks) {
            const int hr = c * 8 + ks;
            if (hr < 63) {
                stage1(hr + 1);
                const int nk = (hr + 1) & 7;
                xb0[(hr + 1) & 1] = *(const bfrag*)(xr0 + nk * 32);
                xb1[(hr + 1) & 1] = *(const bfrag*)(xr1 + nk * 32);
                asm volatile("s_waitcnt vmcnt(3)" ::: "memory");
            } else {
                stage2(0);   // first W2 slab rides through the LN barriers
                asm volatile("s_waitcnt vmcnt(1)" ::: "memory");
            }
            __builtin_amdgcn_sched_barrier(0);
            const bfrag w0 = *(const bfrag*)(wb + (hr & 1) * 512 + lane * 8);
            acc0 = __builtin_amdgcn_mfma_f32_16x16x32_bf16(w0, xb0[hr & 1], acc0, 0, 0, 0);
            acc1 = __builtin_amdgcn_mfma_f32_16x16x32_bf16(w0, xb1[hr & 1], acc1, 0, 0, 0);
        }
        const int kb = c * 128 + wave * 16 + quad * 4;
        #pragma unroll
        for (int mt = 0; mt < 2; ++mt) {
            const int xr = mt * 16 + c16;
            const f32x4 a = mt ? acc1 : acc0;
            b4 o;
            #pragma unroll
            for (int r = 0; r < 4; ++r)
                o[r] = (bf16_t)(a[r] + (float)bias1[c][r]);
            const int ch = ((kb >> 3) ^ (xr & 7));
            *(b4*)(hid + xr * HID + ch * 8 + (kb & 7)) = o;
        }
    }
    __syncthreads();

    // ---- LN(1024) + GELU in LDS: 16 threads/row ----
    {
        const int row = tid >> 4, p = tid & 15;
        float sum = 0.f, ss = 0.f;
        #pragma unroll
        for (int i = 0; i < HID / 128; ++i) {
            const int j0 = p * 8 + i * 128;
            const int ch = ((j0 >> 3) ^ (row & 7));
            bfrag v = *(const bfrag*)(hid + row * HID + ch * 8);
            #pragma unroll
            for (int k = 0; k < 8; ++k) { const float f = (float)v[k]; sum += f; ss += f * f; }
        }
        #pragma unroll
        for (int o = 1; o < 16; o <<= 1) { sum += __shfl_xor(sum, o, 64); ss += __shfl_xor(ss, o, 64); }
        const float mean = sum * (1.0f / HID);
        const float var  = ss * (1.0f / HID) - mean * mean;
        const float rinv = rsqrtf(var + 1e-5f);
        #pragma unroll
        for (int i = 0; i < HID / 128; ++i) {
            const int j0 = p * 8 + i * 128;
            const int ch = ((j0 >> 3) ^ (row & 7));
            bfrag v  = *(const bfrag*)(hid + row * HID + ch * 8);
            bfrag gv = *(const bfrag*)(lng + j0);
            bfrag bv = *(const bfrag*)(lnb + j0);
            bfrag o8;
            #pragma unroll
            for (int k = 0; k < 8; ++k) {
                const float f = ((float)v[k] - mean) * rinv * (float)gv[k] + (float)bv[k];
                o8[k] = (bf16_t)gelu_f(f);
            }
            *(bfrag*)(hid + row * HID + ch * 8) = o8;
        }
    }
    __syncthreads();

    // ---- GEMM2: res[32,256] = hid[32,1024] @ W2, barrier-free ----
    {
        f32x4 acc2[2][2];   // [colpass][mt]
        #pragma unroll
        for (int cp = 0; cp < 2; ++cp)
            #pragma unroll
            for (int mt = 0; mt < 2; ++mt)
                acc2[cp][mt] = f32x4{0.f, 0.f, 0.f, 0.f};
        #pragma unroll
        for (int cp = 0; cp < 2; ++cp) {
            #pragma unroll
            for (int kt = 0; kt < 32; ++kt) {
                const int g = cp * 32 + kt;
                if (g < 63) {
                    stage2(g + 1);
                    asm volatile("s_waitcnt vmcnt(1)" ::: "memory");
                } else {
                    asm volatile("s_waitcnt vmcnt(0)" ::: "memory");
                }
                __builtin_amdgcn_sched_barrier(0);
                const bfrag w0 = *(const bfrag*)(wb + (g & 1) * 512 + lane * 8);
                const int k = kt * 32 + quad * 8;
                bfrag hb[2];
                #pragma unroll
                for (int mt = 0; mt < 2; ++mt) {
                    const int row = mt * 16 + c16;
                    const int ch = ((k >> 3) ^ (row & 7));
                    hb[mt] = *(const bfrag*)(hid + row * HID + ch * 8);
                }
                acc2[cp][0] = __builtin_amdgcn_mfma_f32_16x16x32_bf16(w0, hb[0], acc2[cp][0], 0, 0, 0);
                acc2[cp][1] = __builtin_amdgcn_mfma_f32_16x16x32_bf16(w0, hb[1], acc2[cp][1], 0, 0, 0);
            }
        }

        if (!is_node) {
            if (has_vn) {
                #pragma unroll
                for (int cp = 0; cp < 2; ++cp)
                    #pragma unroll
                    for (int mt = 0; mt < 2; ++mt) {
                        const int cb = cp * 128 + wave * 16 + quad * 4;
                        float* po = vnacc + (rowblk + mt * 16 + c16) * 256 + cb;
                        const f32x4 old = *(const f32x4*)po;
                        f32x4 v;
                        #pragma unroll
                        for (int r = 0; r < 4; ++r) v[r] = old[r] + acc2[cp][mt][r] + (float)bias2[cp][r];
                        *(f32x4*)po = v;
                    }
            }
        } else {
            constexpr int OS = 260;
            float* ot = (float*)hid;
            __syncthreads();
            #pragma unroll
            for (int cp = 0; cp < 2; ++cp)
                #pragma unroll
                for (int mt = 0; mt < 2; ++mt) {
                    const int cb = cp * 128 + wave * 16 + quad * 4;
                    f32x4 v;
                    #pragma unroll
                    for (int r = 0; r < 4; ++r) v[r] = acc2[cp][mt][r] + (float)bias2[cp][r];
                    *(f32x4*)(ot + (mt * 16 + c16) * OS + cb) = v;
                }
            __syncthreads();
            const int row = tid >> 4, p = tid & 15;
            float s = 0.f, q = 0.f;
            #pragma unroll
            for (int i = 0; i < 16; ++i) {
                const float f = ot[row * OS + p + 16 * i];
                s += f; q += f * f;
            }
            #pragma unroll
            for (int o = 1; o < 16; o <<= 1) { s += __shfl_xor(s, o, 64); q += __shfl_xor(q, o, 64); }
            const float mean = s * (1.0f / 256.0f);
            const float var  = q * (1.0f / 256.0f) - mean * mean;
            const float rinv = rsqrtf(var + 1e-5f);
            const size_t rg = (rowblk + row) * 256;
            #pragma unroll
            for (int i = 0; i < 2; ++i) {
                const int j0 = p * 16 + i * 8;
                bfrag gv = *(const bfrag*)(g2 + j0);
                bfrag bv = *(const bfrag*)(b2ln + j0);
                bfrag hv = *(const bfrag*)(hres + rg + j0);
                bfrag o8;
                #pragma unroll
                for (int k = 0; k < 8; ++k) {
                    float f = (ot[row * OS + j0 + k] - mean) * rinv * (float)gv[k] + (float)bv[k];
                    if (gelu_flag) f = gelu_f(f);
                    o8[k] = (bf16_t)(f + (float)hv[k]);
                }
                *(bfrag*)(hres + rg + j0) = o8;
            }
        }
    }
}

// ---------------- small MLP (final projection, HID=256) ----------------
__launch_bounds__(512, 4)
__global__ void k_mlp_proj(const bf16_t* __restrict__ X, const bf16_t* __restrict__ W1T,
                           const bf16_t* __restrict__ b1, const bf16_t* __restrict__ lng,
                           const bf16_t* __restrict__ lnb, const bf16_t* __restrict__ W2T,
                           const bf16_t* __restrict__ b2, float* __restrict__ outf) {
    constexpr int HID = 256;
    constexpr int NP1 = HID / 128;   // 2
    constexpr int NQ2 = HID / 64;    // 4
    __shared__ bf16_t hid[32 * HID];
    __shared__ bf16_t wbuf[8192];
    const int tid  = threadIdx.x;
    const int lane = tid & 63, wave = tid >> 6;
    const int c16  = lane & 15, quad = lane >> 4;
    const size_t rowblk = (size_t)blockIdx.x * 32;

    auto stage = [&](const bf16_t* WT, int KW, int colbase, int k0) {
        #pragma unroll
        for (int j = 0; j < 2; ++j) {
            const int grp    = wave * 2 + j;
            const int colrel = grp * 8 + (lane >> 3);
            const int slot   = lane & 7;
            const int kq     = slot ^ (colrel & 7);
            const bf16_t* gp = WT + (size_t)(colbase + colrel) * KW + k0 + kq * 8;
            bf16_t* lp = &wbuf[(size_t)grp * 512];
            __builtin_amdgcn_global_load_lds(
                (const __attribute__((address_space(1))) void*)gp,
                (__attribute__((address_space(3))) void*)lp, 16, 0, 0);
        }
    };
    auto wfrag = [&](int crel, int g) -> bfrag {
        return *(const bfrag*)(wbuf + crel * 64 + ((g ^ (crel & 7)) * 8));
    };

    const bf16_t* xr0 = X + (rowblk + c16) * 256 + quad * 8;
    const bf16_t* xr1 = X + (rowblk + 16 + c16) * 256 + quad * 8;
    bfrag xa[8][2];
    #pragma unroll
    for (int ks = 0; ks < 8; ++ks) {
        xa[ks][0] = *(const bfrag*)(xr0 + ks * 32);
        xa[ks][1] = *(const bfrag*)(xr1 + ks * 32);
    }

    #pragma unroll
    for (int c = 0; c < NP1; ++c) {
        const int nbase = c * 128 + wave * 16;
        f32x4 acc[2];
        acc[0] = f32x4{0.f, 0.f, 0.f, 0.f};
        acc[1] = f32x4{0.f, 0.f, 0.f, 0.f};
        #pragma unroll
        for (int kc = 0; kc < 4; ++kc) {
            stage(W1T, 256, c * 128, kc * 64);
            __syncthreads();
            #pragma unroll
            for (int s = 0; s < 2; ++s) {
                const int ks = kc * 2 + s;
                const int g  = s * 4 + quad;
                const bfrag w0 = wfrag(wave * 16 + c16, g);
                #pragma unroll
                for (int mt = 0; mt < 2; ++mt)
                    acc[mt] = __builtin_amdgcn_mfma_f32_16x16x32_bf16(
                        w0, xa[ks][mt], acc[mt], 0, 0, 0);
            }
            __syncthreads();
        }
        #pragma unroll
        for (int mt = 0; mt < 2; ++mt) {
            const int kb = nbase + quad * 4;
            const int xr = mt * 16 + c16;
            const b4 bias = *(const b4*)(b1 + kb);
            b4 o;
            #pragma unroll
            for (int r = 0; r < 4; ++r)
                o[r] = (bf16_t)(acc[mt][r] + (float)bias[r]);
            const int ch = ((kb >> 3) ^ (xr & 7));
            *(b4*)(hid + xr * HID + ch * 8 + (kb & 7)) = o;
        }
    }
    __syncthreads();

    {
        const int row = tid >> 4, p = tid & 15;
        float sum = 0.f, ss = 0.f;
        #pragma unroll
        for (int i = 0; i < HID / 128; ++i) {
            const int j0 = p * 8 + i * 128;
            const int ch = ((j0 >> 3) ^ (row & 7));
            bfrag v = *(const bfrag*)(hid + row * HID + ch * 8);
            #pragma unroll
            for (int k = 0; k < 8; ++k) { const float f = (float)v[k]; sum += f; ss += f * f; }
        }
        #pragma unroll
        for (int o = 1; o < 16; o <<= 1) { sum += __shfl_xor(sum, o, 64); ss += __shfl_xor(ss, o, 64); }
        const float mean = sum * (1.0f / HID);
        const float var  = ss * (1.0f / HID) - mean * mean;
        const float rinv = rsqrtf(var + 1e-5f);
        #pragma unroll
        for (int i = 0; i < HID / 128; ++i) {
            const int j0 = p * 8 + i * 128;
            const int ch = ((j0 >> 3) ^ (row & 7));
            bfrag v  = *(const bfrag*)(hid + row * HID + ch * 8);
            bfrag gv = *(const bfrag*)(lng + j0);
            bfrag bv = *(const bfrag*)(lnb + j0);
            bfrag o8;
            #pragma unroll
            for (int k = 0; k < 8; ++k) {
                const float f = ((float)v[k] - mean) * rinv * (float)gv[k] + (float)bv[k];
                o8[k] = (bf16_t)gelu_f(f);
            }
            *(bfrag*)(hid + row * HID + ch * 8) = o8;
        }
    }
    __syncthreads();

    {
        f32x4 acc2[2][2];
        #pragma unroll
        for (int cp = 0; cp < 2; ++cp)
            #pragma unroll
            for (int mt = 0; mt < 2; ++mt)
                acc2[cp][mt] = f32x4{0.f, 0.f, 0.f, 0.f};
        #pragma unroll
        for (int cp = 0; cp < 2; ++cp) {
            for (int q2 = 0; q2 < NQ2; ++q2) {
                stage(W2T, HID, cp * 128, q2 * 64);
                __syncthreads();
                #pragma unroll
                for (int s = 0; s < 2; ++s) {
                    const int g = s * 4 + quad;
                    const bfrag w0 = wfrag(wave * 16 + c16, g);
                    const int k = q2 * 64 + s * 32 + quad * 8;
                    bfrag hb[2];
                    #pragma unroll
                    for (int mt = 0; mt < 2; ++mt) {
                        const int row = mt * 16 + c16;
                        const int ch = ((k >> 3) ^ (row & 7));
                        hb[mt] = *(const bfrag*)(hid + row * HID + ch * 8);
                    }
                    #pragma unroll
                    for (int mt = 0; mt < 2; ++mt)
                        acc2[cp][mt] = __builtin_amdgcn_mfma_f32_16x16x32_bf16(
                            w0, hb[mt], acc2[cp][mt], 0, 0, 0);
                }
                __syncthreads();
            }
        }
        #pragma unroll
        for (int cp = 0; cp < 2; ++cp)
            #pragma unroll
            for (int mt = 0; mt < 2; ++mt) {
                const int cb = cp * 128 + wave * 16 + quad * 4;
                const b4 b2vv = *(const b4*)(b2 + cb);
                f32x4 v;
                #pragma unroll
                for (int r = 0; r < 4; ++r) v[r] = acc2[cp][mt][r] + (float)b2vv[r];
                *(f32x4*)(outf + (rowblk + mt * 16 + c16) * 256 + cb) = v;
            }
    }
}

// ---------------- host launch ----------------
extern "C" void kernel_launch(void* const* d_in, const int* in_sizes, int n_in,
                              void* d_out, int out_size, void* d_ws, size_t ws_size,
                              hipStream_t stream) {
    float* outz = (float*)d_out;

    const bool layout_ok =
        (n_in == 28) &&
        in_sizes[0] == 200000 && in_sizes[1] == 800000 &&
        in_sizes[2] == 400000 && in_sizes[3] == 200000 &&
        in_sizes[4] == 118 * 256 && in_sizes[6] == 5 * 5 * 256 &&
        in_sizes[8] == 5 * 256 * 1024 && in_sizes[27] == 256 &&
        out_size == GG * H;
    if (!layout_ok) {
        k_fill<<<(out_size + 255) / 256, 256, 0, stream>>>(outz, 777.0f, out_size);
        return;
    }

    char* w = (char*)d_ws;
    size_t off = 0;
    auto alloc = [&](size_t bytes) -> void* {
        void* p = w + off;
        off += (bytes + 255) & ~(size_t)255;
        return p;
    };
    bf16_t* h     = (bf16_t*)alloc((size_t)NN * H * 2);
    bf16_t* Xb    = (bf16_t*)alloc((size_t)NN * H * 2);
    float*  vn    = (float*) alloc((size_t)GG * H * 4);
    bf16_t* vpb   = (bf16_t*)alloc((size_t)GG * H * 2);
    bf16_t* hgb   = (bf16_t*)alloc((size_t)GG * H * 2);
    float*  pout2 = (float*) alloc((size_t)GG * H * 4);
    int*    cnt   = (int*)   alloc((size_t)NN * 4);
    int*    slots = (int*)   alloc((size_t)NN * CAP * 4);
    int*    dflag = (int*)   alloc(256);
    bf16_t* cw1T  = (bf16_t*)alloc((size_t)LY * 1024 * 256 * 2);
    bf16_t* cw2T  = (bf16_t*)alloc((size_t)LY * 256 * 1024 * 2);
    bf16_t* vw1T  = (bf16_t*)alloc((size_t)(LY - 1) * 1024 * 256 * 2);
    bf16_t* vw2T  = (bf16_t*)alloc((size_t)(LY - 1) * 256 * 1024 * 2);
    bf16_t* pw1T  = (bf16_t*)alloc((size_t)256 * 256 * 2);
    bf16_t* pw2T  = (bf16_t*)alloc((size_t)256 * 256 * 2);
    bf16_t* atomA = (bf16_t*)alloc((size_t)118 * 256 * 2);
    bf16_t* vneA  = (bf16_t*)alloc(256 * 2);
    bf16_t* bondA = (bf16_t*)alloc((size_t)LY * 5 * 256 * 2);
    bf16_t* epsA  = (bf16_t*)alloc(16 * 2);
    bf16_t* cb1A  = (bf16_t*)alloc((size_t)LY * 1024 * 2);
    bf16_t* clngA = (bf16_t*)alloc((size_t)LY * 1024 * 2);
    bf16_t* clnbA = (bf16_t*)alloc((size_t)LY * 1024 * 2);
    bf16_t* cb2A  = (bf16_t*)alloc((size_t)LY * 256 * 2);
    bf16_t* ngA   = (bf16_t*)alloc((size_t)LY * 256 * 2);
    bf16_t* nbA   = (bf16_t*)alloc((size_t)LY * 256 * 2);
    bf16_t* vb1A  = (bf16_t*)alloc((size_t)(LY - 1) * 1024 * 2);
    bf16_t* vlngA = (bf16_t*)alloc((size_t)(LY - 1) * 1024 * 2);
    bf16_t* vlnbA = (bf16_t*)alloc((size_t)(LY - 1) * 1024 * 2);
    bf16_t* vb2A  = (bf16_t*)alloc((size_t)(LY - 1) * 256 * 2);
    bf16_t* pb1A  = (bf16_t*)alloc(256 * 2);
    bf16_t* plngA = (bf16_t*)alloc(256 * 2);
    bf16_t* plnbA = (bf16_t*)alloc(256 * 2);
    bf16_t* pb2A  = (bf16_t*)alloc(256 * 2);
    if (off > ws_size) {
        k_fill<<<(out_size + 255) / 256, 256, 0, stream>>>(outz, 333.0f, out_size);
        return;
    }

    const int* xi  = (const int*)d_in[0];
    const int* ei  = (const int*)d_in[1];
    const int* ea  = (const int*)d_in[2];

    k_detect<<<1, 64, 0, stream>>>(d_in[8], dflag);

    {
        CvtJobs J{};
        struct { int idx; bf16_t* dst; int n; } cj[18] = {
            {4, atomA, 118 * 256}, {5, vneA, 256}, {6, bondA, LY * 5 * 256}, {7, epsA, LY},
            {9, cb1A, LY * 1024}, {10, clngA, LY * 1024}, {11, clnbA, LY * 1024},
            {13, cb2A, LY * 256}, {14, ngA, LY * 256}, {15, nbA, LY * 256},
            {17, vb1A, (LY - 1) * 1024}, {18, vlngA, (LY - 1) * 1024},
            {19, vlnbA, (LY - 1) * 1024}, {21, vb2A, (LY - 1) * 256},
            {23, pb1A, 256}, {24, plngA, 256}, {25, plnbA, 256}, {27, pb2A, 256},
        };
        int acc = 0;
        J.njobs = 18;
        for (int j = 0; j < 18; ++j) {
            J.src[j] = d_in[cj[j].idx];
            J.dst[j] = cj[j].dst;
            J.pfx[j] = acc;
            acc += cj[j].n;
        }
        J.pfx[18] = acc;
        k_cvt_all<<<(acc + 255) / 256, 256, 0, stream>>>(J, dflag);
    }

    {
        TpJobs J{};
        int nj = 0, acc = 0;
        auto add = [&](int idx, size_t eoff, bf16_t* dst, int R, int C) {
            J.s32[nj] = (const void*)((const float*) d_in[idx] + eoff);
            J.s16[nj] = (const void*)((const bf16_t*)d_in[idx] + eoff);
            J.dst[nj] = dst; J.R[nj] = R; J.C[nj] = C;
            J.pfx[nj] = acc;
            acc += (C / 32) * (R / 32);
            ++nj;
        };
        for (int l = 0; l < LY; ++l) {
            add(8,  (size_t)l * 256 * 1024, cw1T + (size_t)l * 1024 * 256, 256, 1024);
            add(12, (size_t)l * 1024 * 256, cw2T + (size_t)l * 256 * 1024, 1024, 256);
        }
        for (int l = 0; l < LY - 1; ++l) {
            add(16, (size_t)l * 256 * 1024, vw1T + (size_t)l * 1024 * 256, 256, 1024);
            add(20, (size_t)l * 1024 * 256, vw2T + (size_t)l * 256 * 1024, 1024, 256);
        }
        add(22, 0, pw1T, 256, 256);
        add(26, 0, pw2T, 256, 256);
        J.pfx[nj] = acc;
        J.njobs = nj;
        k_tp_all<<<acc, 256, 0, stream>>>(J, dflag);
    }

    k_init_h<<<NN, 256, 0, stream>>>(xi, atomA, h);
    k_init_vn<<<GG, 256, 0, stream>>>(vneA, vn);
    k_zero_cnt<<<(NN + 255) / 256, 256, 0, stream>>>(cnt);
    k_bucket<<<(EE + 255) / 256, 256, 0, stream>>>(ei, ea, cnt, slots);

    for (int l = 0; l < LY; ++l) {
        const int has_vn = (l < LY - 1) ? 1 : 0;
        k_addvn_segmax<<<GG, 128, 0, stream>>>(h, vn, vpb, has_vn);
        k_gather<<<NN, 128, 0, stream>>>(h, bondA + (size_t)l * 5 * H,
                                         cnt, slots, epsA, l, Xb);
        const int lv = (l < LY - 1) ? l : 0;
        k_mlp_dual<<<NBLK_NODE + (has_vn ? NBLK_VN : 0), 512, 0, stream>>>(
            Xb, vpb,
            cw1T + (size_t)l * 1024 * 256, vw1T + (size_t)lv * 1024 * 256,
            cb1A + (size_t)l * 1024,       vb1A + (size_t)lv * 1024,
            clngA + (size_t)l * 1024,      vlngA + (size_t)lv * 1024,
            clnbA + (size_t)l * 1024,      vlnbA + (size_t)lv * 1024,
            cw2T + (size_t)l * 256 * 1024, vw2T + (size_t)lv * 256 * 1024,
            cb2A + (size_t)l * 256,        vb2A + (size_t)lv * 256,
            ngA + (size_t)l * H, nbA + (size_t)l * H,
            h, vn, has_vn, NBLK_NODE, has_vn);
    }

    k_graphsum<<<GG, 128, 0, stream>>>(h, hgb);
    k_mlp_proj<<<GG / 32, 512, 0, stream>>>(hgb, pw1T, pb1A, plngA, plnbA, pw2T, pb2A, pout2);
    k_norm<<<GG, 256, 0, stream>>>(pout2, outz);
}

// Round 4
// 4629.879 us; speedup vs baseline: 1.8465x; 1.8465x over previous
//
#include <hip/hip_runtime.h>
#include <math.h>

typedef __bf16 bf16_t;
typedef __bf16 bfrag  __attribute__((ext_vector_type(8)));  // 8 bf16 (MFMA A/B frag)
typedef __bf16 b4     __attribute__((ext_vector_type(4)));  // 4 bf16 = 8B vector store
typedef __bf16 b2v    __attribute__((ext_vector_type(2)));  // 2 bf16 = 4B vector
typedef float  f32x4  __attribute__((ext_vector_type(4)));  // MFMA C/D frag

static constexpr int LY  = 5;
static constexpr int H   = 256;
static constexpr int NN  = 200000;
static constexpr int EE  = 400000;
static constexpr int GG  = 8000;
static constexpr int NPG = 25;
static constexpr int CAP = 24;   // max buffered in-edges/node (Poisson(2): P(>24) ~ 1e-17)
static constexpr int MROW = 64;                  // rows per MLP block
static constexpr int NBLK_NODE = NN / MROW;      // 3125
static constexpr int NBLK_VN   = GG / MROW;      // 125

// tanh-approx GELU (~8 VALU ops; |delta| vs exact erf-gelu ~3e-4 absolute)
__device__ __forceinline__ float gelu_f(float x) {
    const float y = 0.7978845608028654f * x * (1.0f + 0.044715f * x * x);
    const float e = __expf(2.0f * y);
    const float t = 1.0f - 2.0f / (e + 1.0f);
    return 0.5f * x * (1.0f + t);
}

// ---------------- diagnostics ----------------
__global__ void k_fill(float* __restrict__ out, float v, int n) {
    const int i = blockIdx.x * 256 + threadIdx.x;
    if (i < n) out[i] = v;
}

// ---------------- dtype detection ----------------
__global__ void k_detect(const void* __restrict__ probe, int* __restrict__ flag) {
    const bf16_t* p = (const bf16_t*)probe;
    int bad = 0;
    for (int i = threadIdx.x; i < 256; i += 64) {
        const float v = (float)p[i];
        if (!(v == v) || fabsf(v) > 1000.0f) bad = 1;
    }
    const int any = __any(bad) ? 1 : 0;
    if (threadIdx.x == 0) *flag = any;
}

// ---------------- batched param conversion (1 launch) ----------------
struct CvtJobs {
    const void* src[18];
    bf16_t*     dst[18];
    int         pfx[19];
    int         njobs;
};
__global__ void k_cvt_all(CvtJobs J, const int* __restrict__ flag) {
    const int i = blockIdx.x * 256 + threadIdx.x;
    if (i >= J.pfx[J.njobs]) return;
    int j = 0;
    while (i >= J.pfx[j + 1]) ++j;
    const int loc = i - J.pfx[j];
    if (*flag) J.dst[j][loc] = (bf16_t)((const float*)J.src[j])[loc];
    else       J.dst[j][loc] = ((const bf16_t*)J.src[j])[loc];
}

// ---------------- batched weight transpose (1 launch) ----------------
struct TpJobs {
    const void* s32[22];
    const void* s16[22];
    bf16_t*     dst[22];
    int R[22], C[22];
    int pfx[23];
    int njobs;
};
__global__ void k_tp_all(TpJobs J, const int* __restrict__ flag) {
    __shared__ bf16_t t[32][33];
    const int tile = blockIdx.x;
    int j = 0;
    while (tile >= J.pfx[j + 1]) ++j;
    const int tl = tile - J.pfx[j];
    const int C = J.C[j], R = J.R[j];
    const int ntx = C / 32;
    const int c0 = (tl % ntx) * 32, r0 = (tl / ntx) * 32;
    const int f = *flag;
    const int tx = threadIdx.x & 31, ty = threadIdx.x >> 5;
    #pragma unroll
    for (int i = 0; i < 4; ++i) {
        const int r = ty + i * 8;
        const size_t idx = (size_t)(r0 + r) * C + c0 + tx;
        t[r][tx] = f ? (bf16_t)((const float*)J.s32[j])[idx] : ((const bf16_t*)J.s16[j])[idx];
    }
    __syncthreads();
    #pragma unroll
    for (int i = 0; i < 4; ++i) {
        const int r = ty + i * 8;
        J.dst[j][(size_t)(c0 + r) * R + r0 + tx] = t[tx][r];
    }
}

// ---------------- init ----------------
__global__ void k_init_h(const int* __restrict__ x, const bf16_t* __restrict__ atom,
                         bf16_t* __restrict__ h) {
    const size_t idx = (size_t)blockIdx.x * 256 + threadIdx.x;
    const int row = (int)(idx >> 8), col = (int)(idx & 255);
    h[idx] = atom[(size_t)x[row] * H + col];
}

__global__ void k_init_vn(const bf16_t* __restrict__ vne, float* __restrict__ vn) {
    const size_t idx = (size_t)blockIdx.x * 256 + threadIdx.x;
    vn[idx] = (float)vne[idx & 255];
}

// ---------------- edge bucket build (packed src|attr slots) ----------------
__global__ void k_zero_cnt(int* __restrict__ cnt) {
    const int i = blockIdx.x * 256 + threadIdx.x;
    if (i < NN) cnt[i] = 0;
}

// slots hold src | (attr << 18)  (src < 2^18 since NN=200000 < 262144; attr < 8)
__global__ void k_bucket(const int* __restrict__ ei, const int* __restrict__ ea,
                         int* __restrict__ cnt, int* __restrict__ slots) {
    const int e = blockIdx.x * 256 + threadIdx.x;
    if (e >= EE) return;
    const int d = ei[EE + e];
    const int s = ei[e];
    const int a = ea[e];
    const int slot = atomicAdd(&cnt[d], 1);
    if (slot < CAP) slots[(size_t)d * CAP + slot] = s | (a << 18);
}

// ---------------- fused addvn + segment_max (block = 1 graph, bf16x2 lanes) ----------------
__global__ void k_addvn_segmax(bf16_t* __restrict__ h, const float* __restrict__ vn,
                               bf16_t* __restrict__ vp, int do_max) {
    const int g = blockIdx.x, t = threadIdx.x;   // 128 threads; cols 2t, 2t+1
    const float2 v = *(const float2*)(vn + (size_t)g * H + 2 * t);
    float mx0 = -1e30f, mx1 = -1e30f;
    #pragma unroll 5
    for (int i = 0; i < NPG; ++i) {
        bf16_t* p = h + ((size_t)g * NPG + i) * H + 2 * t;
        const b2v hv = *(const b2v*)p;
        const float h0 = (float)hv[0] + v.x;
        const float h1 = (float)hv[1] + v.y;
        b2v o; o[0] = (bf16_t)h0; o[1] = (bf16_t)h1;
        *(b2v*)p = o;
        mx0 = fmaxf(mx0, h0); mx1 = fmaxf(mx1, h1);
    }
    if (do_max) {
        b2v o; o[0] = (bf16_t)mx0; o[1] = (bf16_t)mx1;
        *(b2v*)(vp + (size_t)g * H + 2 * t) = o;
    }
}

// ---------------- edge gather (bf16x2 lanes; packed slots: 2-level chain) ----------------
__global__ void k_gather(const bf16_t* __restrict__ h,
                         const bf16_t* __restrict__ bondl,
                         const int* __restrict__ cnt, const int* __restrict__ slots,
                         const bf16_t* __restrict__ epsb, int l, bf16_t* __restrict__ Xb) {
    const int n = blockIdx.x, t = threadIdx.x;   // 128 threads; cols 2t, 2t+1
    int deg = cnt[n];
    if (deg > CAP) deg = CAP;
    float m0 = 0.0f, m1 = 0.0f;
    for (int i = 0; i < deg; ++i) {
        const int p = slots[(size_t)n * CAP + i];
        const int s = p & 0x3FFFF;
        const int a = p >> 18;
        const b2v hv = *(const b2v*)(h + (size_t)s * H + 2 * t);
        const b2v bv = *(const b2v*)(bondl + (size_t)a * H + 2 * t);
        m0 += gelu_f((float)hv[0] + (float)bv[0]);
        m1 += gelu_f((float)hv[1] + (float)bv[1]);
    }
    const float eps1 = 1.0f + (float)epsb[l];
    const b2v hn = *(const b2v*)(h + (size_t)n * H + 2 * t);
    b2v o;
    o[0] = (bf16_t)(eps1 * (float)hn[0] + m0);
    o[1] = (bf16_t)(eps1 * (float)hn[1] + m1);
    *(b2v*)(Xb + (size_t)n * H + 2 * t) = o;
}

__global__ void k_graphsum(const bf16_t* __restrict__ h, bf16_t* __restrict__ hg) {
    const int g = blockIdx.x, t = threadIdx.x;   // 128 threads
    float s0 = 0.0f, s1 = 0.0f;
    #pragma unroll 5
    for (int i = 0; i < NPG; ++i) {
        const b2v hv = *(const b2v*)(h + ((size_t)g * NPG + i) * H + 2 * t);
        s0 += (float)hv[0]; s1 += (float)hv[1];
    }
    b2v o; o[0] = (bf16_t)s0; o[1] = (bf16_t)s1;
    *(b2v*)(hg + (size_t)g * H + 2 * t) = o;
}

__global__ void k_norm(const float* __restrict__ z, float* __restrict__ out) {
    const int row = blockIdx.x, t = threadIdx.x;
    const size_t idx = (size_t)row * H + t;
    const float v = z[idx];
    float q = v * v;
    #pragma unroll
    for (int o = 32; o > 0; o >>= 1) q += __shfl_xor(q, o, 64);
    __shared__ float rq[4];
    const int wave = t >> 6, lane = t & 63;
    if (lane == 0) rq[wave] = q;
    __syncthreads();
    q = rq[0] + rq[1] + rq[2] + rq[3];
    out[idx] = v * rsqrtf(q);
}

// ---------------- fused MLP dual: node (LN+res) + vn (accumulate) in ONE dispatch ----------------
// M=64 amortized staging (round-0 structure, doubled rows): 1024 threads =
// 16 waves. Waves 0-7 compute rows 0-31, waves 8-15 rows 32-63 — per-wave
// code is IDENTICAL to the proven 32-row kernel (same fragment maps, same
// VGPR footprint). The 16 KB weight slab per round is staged by 16 waves
// (1 KB each) and consumed by 2x the MFMA work, so the fixed per-round
// barrier+vmcnt(0) drain (~500-700 cy, the round-0 bottleneck at MfmaUtil
// 13%) is amortized over twice the output: block count halves (6500->3250),
// rounds/block unchanged. LDS = 128 KB hid + 16 KB slab = 144 KB ->
// 1 block/CU but SAME 16 waves/CU as before. VGPR capped at 128 by
// __launch_bounds__(1024,4) so the 16-wave block is launchable.
__launch_bounds__(1024, 4)
__global__ void k_mlp_dual(const bf16_t* __restrict__ Xn, const bf16_t* __restrict__ Xv,
                           const bf16_t* __restrict__ nW1T, const bf16_t* __restrict__ vW1T,
                           const bf16_t* __restrict__ nb1, const bf16_t* __restrict__ vb1,
                           const bf16_t* __restrict__ nlng, const bf16_t* __restrict__ vlng,
                           const bf16_t* __restrict__ nlnb, const bf16_t* __restrict__ vlnb,
                           const bf16_t* __restrict__ nW2T, const bf16_t* __restrict__ vW2T,
                           const bf16_t* __restrict__ nb2, const bf16_t* __restrict__ vb2,
                           const bf16_t* __restrict__ g2, const bf16_t* __restrict__ b2ln,
                           bf16_t* __restrict__ hres, float* __restrict__ vnacc,
                           int gelu_flag, int nblk_node, int has_vn) {
    constexpr int HID = 1024;
    __shared__ __align__(16) bf16_t hid[MROW * HID];  // 128 KB
    __shared__ __align__(16) bf16_t wbuf[8192];       // 16 KB slab (128 cols x 64 k)
    const int tid  = threadIdx.x;
    const int lane = tid & 63, wave = tid >> 6;       // wave in [0,16)
    const int c16  = lane & 15, quad = lane >> 4;
    const int wcol = wave & 7;                        // col-group within pass
    const int wrow = wave >> 3;                       // row half (0 or 1)

    const bool is_node = (int)blockIdx.x < nblk_node;
    const size_t rowblk = is_node ? (size_t)blockIdx.x * MROW
                                  : (size_t)((int)blockIdx.x - nblk_node) * MROW;
    const bf16_t* X    = is_node ? Xn   : Xv;
    const bf16_t* W1T  = is_node ? nW1T : vW1T;
    const bf16_t* W2T  = is_node ? nW2T : vW2T;
    const bf16_t* b1   = is_node ? nb1  : vb1;
    const bf16_t* lng  = is_node ? nlng : vlng;
    const bf16_t* lnb  = is_node ? nlnb : vlnb;
    const bf16_t* b2   = is_node ? nb2  : vb2;

    // Staging: 16 waves x 1 KB each -> 16 KB slab (128 cols x 64 k), 8-slot
    // source-XOR (same layout as the proven 32-row kernel).
    auto stage = [&](const bf16_t* WT, int KW, int colbase, int k0) {
        const int grp    = wave;                       // 0..15
        const int colrel = grp * 8 + (lane >> 3);      // 0..127
        const int slot   = lane & 7;                   // 0..7
        const int kq     = slot ^ (colrel & 7);
        const bf16_t* gp = WT + (size_t)(colbase + colrel) * KW + k0 + kq * 8;
        bf16_t* lp = &wbuf[(size_t)grp * 512];         // wave-uniform base
        __builtin_amdgcn_global_load_lds(
            (const __attribute__((address_space(1))) void*)gp,
            (__attribute__((address_space(3))) void*)lp, 16, 0, 0);
    };
    auto wfrag = [&](int crel, int g) -> bfrag {
        return *(const bfrag*)(wbuf + crel * 64 + ((g ^ (crel & 7)) * 8));
    };

    // ---- X a-frags (read once; 2 row-tiles per wave, offset by wrow*32) ----
    const bf16_t* xr0 = X + (rowblk + wrow * 32 + c16) * 256 + quad * 8;
    const bf16_t* xr1 = X + (rowblk + wrow * 32 + 16 + c16) * 256 + quad * 8;
    bfrag xa[8][2];
    #pragma unroll
    for (int ks = 0; ks < 8; ++ks) {
        xa[ks][0] = *(const bfrag*)(xr0 + ks * 32);
        xa[ks][1] = *(const bfrag*)(xr1 + ks * 32);
    }

    // ---- GEMM1: hid[64,1024] = X[64,256] @ W1 ----
    #pragma unroll
    for (int c = 0; c < 8; ++c) {
        const int nbase = c * 128 + wcol * 16;
        f32x4 acc[2];
        acc[0] = f32x4{0.f, 0.f, 0.f, 0.f};
        acc[1] = f32x4{0.f, 0.f, 0.f, 0.f};
        #pragma unroll
        for (int kc = 0; kc < 4; ++kc) {
            stage(W1T, 256, c * 128, kc * 64);
            __syncthreads();
            #pragma unroll
            for (int s = 0; s < 2; ++s) {
                const int ks = kc * 2 + s;
                const int g  = s * 4 + quad;
                const bfrag w0 = wfrag(wcol * 16 + c16, g);
                #pragma unroll
                for (int mt = 0; mt < 2; ++mt)
                    acc[mt] = __builtin_amdgcn_mfma_f32_16x16x32_bf16(
                        w0, xa[ks][mt], acc[mt], 0, 0, 0);
            }
            __syncthreads();
        }
        #pragma unroll
        for (int mt = 0; mt < 2; ++mt) {
            const int kb = nbase + quad * 4;
            const int xr = wrow * 32 + mt * 16 + c16;
            const b4 bias = *(const b4*)(b1 + kb);
            b4 o;
            #pragma unroll
            for (int r = 0; r < 4; ++r)
                o[r] = (bf16_t)(acc[mt][r] + (float)bias[r]);
            const int ch = ((kb >> 3) ^ (xr & 7));
            *(b4*)(hid + xr * HID + ch * 8 + (kb & 7)) = o;
        }
    }
    __syncthreads();

    // ---- LN(1024) + GELU in LDS: 16 threads/row, 64 rows ----
    {
        const int row = tid >> 4, p = tid & 15;
        float sum = 0.f, ss = 0.f;
        #pragma unroll
        for (int i = 0; i < HID / 128; ++i) {
            const int j0 = p * 8 + i * 128;
            const int ch = ((j0 >> 3) ^ (row & 7));
            bfrag v = *(const bfrag*)(hid + row * HID + ch * 8);
            #pragma unroll
            for (int k = 0; k < 8; ++k) { const float f = (float)v[k]; sum += f; ss += f * f; }
        }
        #pragma unroll
        for (int o = 1; o < 16; o <<= 1) { sum += __shfl_xor(sum, o, 64); ss += __shfl_xor(ss, o, 64); }
        const float mean = sum * (1.0f / HID);
        const float var  = ss * (1.0f / HID) - mean * mean;
        const float rinv = rsqrtf(var + 1e-5f);
        #pragma unroll
        for (int i = 0; i < HID / 128; ++i) {
            const int j0 = p * 8 + i * 128;
            const int ch = ((j0 >> 3) ^ (row & 7));
            bfrag v  = *(const bfrag*)(hid + row * HID + ch * 8);
            bfrag gv = *(const bfrag*)(lng + j0);
            bfrag bv = *(const bfrag*)(lnb + j0);
            bfrag o8;
            #pragma unroll
            for (int k = 0; k < 8; ++k) {
                const float f = ((float)v[k] - mean) * rinv * (float)gv[k] + (float)bv[k];
                o8[k] = (bf16_t)gelu_f(f);
            }
            *(bfrag*)(hid + row * HID + ch * 8) = o8;
        }
    }
    __syncthreads();

    // ---- GEMM2: res[64,256] = hid[64,1024] @ W2 ----
    {
        f32x4 acc2[2][2];   // [colpass][mt]
        #pragma unroll
        for (int cp = 0; cp < 2; ++cp)
            #pragma unroll
            for (int mt = 0; mt < 2; ++mt)
                acc2[cp][mt] = f32x4{0.f, 0.f, 0.f, 0.f};
        #pragma unroll
        for (int cp = 0; cp < 2; ++cp) {
            for (int q2 = 0; q2 < 16; ++q2) {
                stage(W2T, HID, cp * 128, q2 * 64);
                __syncthreads();
                #pragma unroll
                for (int s = 0; s < 2; ++s) {
                    const int g = s * 4 + quad;
                    const bfrag w0 = wfrag(wcol * 16 + c16, g);
                    const int k = q2 * 64 + s * 32 + quad * 8;
                    bfrag hb[2];
                    #pragma unroll
                    for (int mt = 0; mt < 2; ++mt) {
                        const int row = wrow * 32 + mt * 16 + c16;
                        const int ch = ((k >> 3) ^ (row & 7));
                        hb[mt] = *(const bfrag*)(hid + row * HID + ch * 8);
                    }
                    #pragma unroll
                    for (int mt = 0; mt < 2; ++mt)
                        acc2[cp][mt] = __builtin_amdgcn_mfma_f32_16x16x32_bf16(
                            w0, hb[mt], acc2[cp][mt], 0, 0, 0);
                }
                __syncthreads();
            }
        }

        if (!is_node) {
            if (has_vn) {
                #pragma unroll
                for (int cp = 0; cp < 2; ++cp)
                    #pragma unroll
                    for (int mt = 0; mt < 2; ++mt) {
                        const int cb = cp * 128 + wcol * 16 + quad * 4;
                        const b4 b2vv = *(const b4*)(b2 + cb);
                        float* po = vnacc + (rowblk + wrow * 32 + mt * 16 + c16) * 256 + cb;
                        const f32x4 old = *(const f32x4*)po;
                        f32x4 v;
                        #pragma unroll
                        for (int r = 0; r < 4; ++r) v[r] = old[r] + acc2[cp][mt][r] + (float)b2vv[r];
                        *(f32x4*)po = v;
                    }
            }
        } else {
            constexpr int OS = 260;
            float* ot = (float*)hid;   // 64*260*4 = 66.5 KB, fits the 128 KB hid region
            __syncthreads();
            #pragma unroll
            for (int cp = 0; cp < 2; ++cp)
                #pragma unroll
                for (int mt = 0; mt < 2; ++mt) {
                    const int cb = cp * 128 + wcol * 16 + quad * 4;
                    const b4 b2vv = *(const b4*)(b2 + cb);
                    f32x4 v;
                    #pragma unroll
                    for (int r = 0; r < 4; ++r) v[r] = acc2[cp][mt][r] + (float)b2vv[r];
                    *(f32x4*)(ot + (wrow * 32 + mt * 16 + c16) * OS + cb) = v;
                }
            __syncthreads();
            const int row = tid >> 4, p = tid & 15;
            float s = 0.f, q = 0.f;
            #pragma unroll
            for (int i = 0; i < 16; ++i) {
                const float f = ot[row * OS + p + 16 * i];
                s += f; q += f * f;
            }
            #pragma unroll
            for (int o = 1; o < 16; o <<= 1) { s += __shfl_xor(s, o, 64); q += __shfl_xor(q, o, 64); }
            const float mean = s * (1.0f / 256.0f);
            const float var  = q * (1.0f / 256.0f) - mean * mean;
            const float rinv = rsqrtf(var + 1e-5f);
            const size_t rg = (rowblk + row) * 256;
            #pragma unroll
            for (int i = 0; i < 2; ++i) {
                const int j0 = p * 16 + i * 8;
                bfrag gv = *(const bfrag*)(g2 + j0);
                bfrag bv = *(const bfrag*)(b2ln + j0);
                bfrag hv = *(const bfrag*)(hres + rg + j0);
                bfrag o8;
                #pragma unroll
                for (int k = 0; k < 8; ++k) {
                    float f = (ot[row * OS + j0 + k] - mean) * rinv * (float)gv[k] + (float)bv[k];
                    if (gelu_flag) f = gelu_f(f);
                    o8[k] = (bf16_t)(f + (float)hv[k]);
                }
                *(bfrag*)(hres + rg + j0) = o8;
            }
        }
    }
}

// ---------------- small MLP (final projection, HID=256) ----------------
__launch_bounds__(512, 4)
__global__ void k_mlp_proj(const bf16_t* __restrict__ X, const bf16_t* __restrict__ W1T,
                           const bf16_t* __restrict__ b1, const bf16_t* __restrict__ lng,
                           const bf16_t* __restrict__ lnb, const bf16_t* __restrict__ W2T,
                           const bf16_t* __restrict__ b2, float* __restrict__ outf) {
    constexpr int HID = 256;
    constexpr int NP1 = HID / 128;   // 2
    constexpr int NQ2 = HID / 64;    // 4
    __shared__ bf16_t hid[32 * HID];
    __shared__ bf16_t wbuf[8192];
    const int tid  = threadIdx.x;
    const int lane = tid & 63, wave = tid >> 6;
    const int c16  = lane & 15, quad = lane >> 4;
    const size_t rowblk = (size_t)blockIdx.x * 32;

    auto stage = [&](const bf16_t* WT, int KW, int colbase, int k0) {
        #pragma unroll
        for (int j = 0; j < 2; ++j) {
            const int grp    = wave * 2 + j;
            const int colrel = grp * 8 + (lane >> 3);
            const int slot   = lane & 7;
            const int kq     = slot ^ (colrel & 7);
            const bf16_t* gp = WT + (size_t)(colbase + colrel) * KW + k0 + kq * 8;
            bf16_t* lp = &wbuf[(size_t)grp * 512];
            __builtin_amdgcn_global_load_lds(
                (const __attribute__((address_space(1))) void*)gp,
                (__attribute__((address_space(3))) void*)lp, 16, 0, 0);
        }
    };
    auto wfrag = [&](int crel, int g) -> bfrag {
        return *(const bfrag*)(wbuf + crel * 64 + ((g ^ (crel & 7)) * 8));
    };

    const bf16_t* xr0 = X + (rowblk + c16) * 256 + quad * 8;
    const bf16_t* xr1 = X + (rowblk + 16 + c16) * 256 + quad * 8;
    bfrag xa[8][2];
    #pragma unroll
    for (int ks = 0; ks < 8; ++ks) {
        xa[ks][0] = *(const bfrag*)(xr0 + ks * 32);
        xa[ks][1] = *(const bfrag*)(xr1 + ks * 32);
    }

    #pragma unroll
    for (int c = 0; c < NP1; ++c) {
        const int nbase = c * 128 + wave * 16;
        f32x4 acc[2];
        acc[0] = f32x4{0.f, 0.f, 0.f, 0.f};
        acc[1] = f32x4{0.f, 0.f, 0.f, 0.f};
        #pragma unroll
        for (int kc = 0; kc < 4; ++kc) {
            stage(W1T, 256, c * 128, kc * 64);
            __syncthreads();
            #pragma unroll
            for (int s = 0; s < 2; ++s) {
                const int ks = kc * 2 + s;
                const int g  = s * 4 + quad;
                const bfrag w0 = wfrag(wave * 16 + c16, g);
                #pragma unroll
                for (int mt = 0; mt < 2; ++mt)
                    acc[mt] = __builtin_amdgcn_mfma_f32_16x16x32_bf16(
                        w0, xa[ks][mt], acc[mt], 0, 0, 0);
            }
            __syncthreads();
        }
        #pragma unroll
        for (int mt = 0; mt < 2; ++mt) {
            const int kb = nbase + quad * 4;
            const int xr = mt * 16 + c16;
            const b4 bias = *(const b4*)(b1 + kb);
            b4 o;
            #pragma unroll
            for (int r = 0; r < 4; ++r)
                o[r] = (bf16_t)(acc[mt][r] + (float)bias[r]);
            const int ch = ((kb >> 3) ^ (xr & 7));
            *(b4*)(hid + xr * HID + ch * 8 + (kb & 7)) = o;
        }
    }
    __syncthreads();

    {
        const int row = tid >> 4, p = tid & 15;
        float sum = 0.f, ss = 0.f;
        #pragma unroll
        for (int i = 0; i < HID / 128; ++i) {
            const int j0 = p * 8 + i * 128;
            const int ch = ((j0 >> 3) ^ (row & 7));
            bfrag v = *(const bfrag*)(hid + row * HID + ch * 8);
            #pragma unroll
            for (int k = 0; k < 8; ++k) { const float f = (float)v[k]; sum += f; ss += f * f; }
        }
        #pragma unroll
        for (int o = 1; o < 16; o <<= 1) { sum += __shfl_xor(sum, o, 64); ss += __shfl_xor(ss, o, 64); }
        const float mean = sum * (1.0f / HID);
        const float var  = ss * (1.0f / HID) - mean * mean;
        const float rinv = rsqrtf(var + 1e-5f);
        #pragma unroll
        for (int i = 0; i < HID / 128; ++i) {
            const int j0 = p * 8 + i * 128;
            const int ch = ((j0 >> 3) ^ (row & 7));
            bfrag v  = *(const bfrag*)(hid + row * HID + ch * 8);
            bfrag gv = *(const bfrag*)(lng + j0);
            bfrag bv = *(const bfrag*)(lnb + j0);
            bfrag o8;
            #pragma unroll
            for (int k = 0; k < 8; ++k) {
                const float f = ((float)v[k] - mean) * rinv * (float)gv[k] + (float)bv[k];
                o8[k] = (bf16_t)gelu_f(f);
            }
            *(bfrag*)(hid + row * HID + ch * 8) = o8;
        }
    }
    __syncthreads();

    {
        f32x4 acc2[2][2];
        #pragma unroll
        for (int cp = 0; cp < 2; ++cp)
            #pragma unroll
            for (int mt = 0; mt < 2; ++mt)
                acc2[cp][mt] = f32x4{0.f, 0.f, 0.f, 0.f};
        #pragma unroll
        for (int cp = 0; cp < 2; ++cp) {
            for (int q2 = 0; q2 < NQ2; ++q2) {
                stage(W2T, HID, cp * 128, q2 * 64);
                __syncthreads();
                #pragma unroll
                for (int s = 0; s < 2; ++s) {
                    const int g = s * 4 + quad;
                    const bfrag w0 = wfrag(wave * 16 + c16, g);
                    const int k = q2 * 64 + s * 32 + quad * 8;
                    bfrag hb[2];
                    #pragma unroll
                    for (int mt = 0; mt < 2; ++mt) {
                        const int row = mt * 16 + c16;
                        const int ch = ((k >> 3) ^ (row & 7));
                        hb[mt] = *(const bfrag*)(hid + row * HID + ch * 8);
                    }
                    #pragma unroll
                    for (int mt = 0; mt < 2; ++mt)
                        acc2[cp][mt] = __builtin_amdgcn_mfma_f32_16x16x32_bf16(
                            w0, hb[mt], acc2[cp][mt], 0, 0, 0);
                }
                __syncthreads();
            }
        }
        #pragma unroll
        for (int cp = 0; cp < 2; ++cp)
            #pragma unroll
            for (int mt = 0; mt < 2; ++mt) {
                const int cb = cp * 128 + wave * 16 + quad * 4;
                const b4 b2vv = *(const b4*)(b2 + cb);
                f32x4 v;
                #pragma unroll
                for (int r = 0; r < 4; ++r) v[r] = acc2[cp][mt][r] + (float)b2vv[r];
                *(f32x4*)(outf + (rowblk + mt * 16 + c16) * 256 + cb) = v;
            }
    }
}

// ---------------- host launch ----------------
extern "C" void kernel_launch(void* const* d_in, const int* in_sizes, int n_in,
                              void* d_out, int out_size, void* d_ws, size_t ws_size,
                              hipStream_t stream) {
    float* outz = (float*)d_out;

    const bool layout_ok =
        (n_in == 28) &&
        in_sizes[0] == 200000 && in_sizes[1] == 800000 &&
        in_sizes[2] == 400000 && in_sizes[3] == 200000 &&
        in_sizes[4] == 118 * 256 && in_sizes[6] == 5 * 5 * 256 &&
        in_sizes[8] == 5 * 256 * 1024 && in_sizes[27] == 256 &&
        out_size == GG * H;
    if (!layout_ok) {
        k_fill<<<(out_size + 255) / 256, 256, 0, stream>>>(outz, 777.0f, out_size);
        return;
    }

    char* w = (char*)d_ws;
    size_t off = 0;
    auto alloc = [&](size_t bytes) -> void* {
        void* p = w + off;
        off += (bytes + 255) & ~(size_t)255;
        return p;
    };
    bf16_t* h     = (bf16_t*)alloc((size_t)NN * H * 2);
    bf16_t* Xb    = (bf16_t*)alloc((size_t)NN * H * 2);
    float*  vn    = (float*) alloc((size_t)GG * H * 4);
    bf16_t* vpb   = (bf16_t*)alloc((size_t)GG * H * 2);
    bf16_t* hgb   = (bf16_t*)alloc((size_t)GG * H * 2);
    float*  pout2 = (float*) alloc((size_t)GG * H * 4);
    int*    cnt   = (int*)   alloc((size_t)NN * 4);
    int*    slots = (int*)   alloc((size_t)NN * CAP * 4);
    int*    dflag = (int*)   alloc(256);
    bf16_t* cw1T  = (bf16_t*)alloc((size_t)LY * 1024 * 256 * 2);
    bf16_t* cw2T  = (bf16_t*)alloc((size_t)LY * 256 * 1024 * 2);
    bf16_t* vw1T  = (bf16_t*)alloc((size_t)(LY - 1) * 1024 * 256 * 2);
    bf16_t* vw2T  = (bf16_t*)alloc((size_t)(LY - 1) * 256 * 1024 * 2);
    bf16_t* pw1T  = (bf16_t*)alloc((size_t)256 * 256 * 2);
    bf16_t* pw2T  = (bf16_t*)alloc((size_t)256 * 256 * 2);
    bf16_t* atomA = (bf16_t*)alloc((size_t)118 * 256 * 2);
    bf16_t* vneA  = (bf16_t*)alloc(256 * 2);
    bf16_t* bondA = (bf16_t*)alloc((size_t)LY * 5 * 256 * 2);
    bf16_t* epsA  = (bf16_t*)alloc(16 * 2);
    bf16_t* cb1A  = (bf16_t*)alloc((size_t)LY * 1024 * 2);
    bf16_t* clngA = (bf16_t*)alloc((size_t)LY * 1024 * 2);
    bf16_t* clnbA = (bf16_t*)alloc((size_t)LY * 1024 * 2);
    bf16_t* cb2A  = (bf16_t*)alloc((size_t)LY * 256 * 2);
    bf16_t* ngA   = (bf16_t*)alloc((size_t)LY * 256 * 2);
    bf16_t* nbA   = (bf16_t*)alloc((size_t)LY * 256 * 2);
    bf16_t* vb1A  = (bf16_t*)alloc((size_t)(LY - 1) * 1024 * 2);
    bf16_t* vlngA = (bf16_t*)alloc((size_t)(LY - 1) * 1024 * 2);
    bf16_t* vlnbA = (bf16_t*)alloc((size_t)(LY - 1) * 1024 * 2);
    bf16_t* vb2A  = (bf16_t*)alloc((size_t)(LY - 1) * 256 * 2);
    bf16_t* pb1A  = (bf16_t*)alloc(256 * 2);
    bf16_t* plngA = (bf16_t*)alloc(256 * 2);
    bf16_t* plnbA = (bf16_t*)alloc(256 * 2);
    bf16_t* pb2A  = (bf16_t*)alloc(256 * 2);
    if (off > ws_size) {
        k_fill<<<(out_size + 255) / 256, 256, 0, stream>>>(outz, 333.0f, out_size);
        return;
    }

    const int* xi  = (const int*)d_in[0];
    const int* ei  = (const int*)d_in[1];
    const int* ea  = (const int*)d_in[2];

    k_detect<<<1, 64, 0, stream>>>(d_in[8], dflag);

    {
        CvtJobs J{};
        struct { int idx; bf16_t* dst; int n; } cj[18] = {
            {4, atomA, 118 * 256}, {5, vneA, 256}, {6, bondA, LY * 5 * 256}, {7, epsA, LY},
            {9, cb1A, LY * 1024}, {10, clngA, LY * 1024}, {11, clnbA, LY * 1024},
            {13, cb2A, LY * 256}, {14, ngA, LY * 256}, {15, nbA, LY * 256},
            {17, vb1A, (LY - 1) * 1024}, {18, vlngA, (LY - 1) * 1024},
            {19, vlnbA, (LY - 1) * 1024}, {21, vb2A, (LY - 1) * 256},
            {23, pb1A, 256}, {24, plngA, 256}, {25, plnbA, 256}, {27, pb2A, 256},
        };
        int acc = 0;
        J.njobs = 18;
        for (int j = 0; j < 18; ++j) {
            J.src[j] = d_in[cj[j].idx];
            J.dst[j] = cj[j].dst;
            J.pfx[j] = acc;
            acc += cj[j].n;
        }
        J.pfx[18] = acc;
        k_cvt_all<<<(acc + 255) / 256, 256, 0, stream>>>(J, dflag);
    }

    {
        TpJobs J{};
        int nj = 0, acc = 0;
        auto add = [&](int idx, size_t eoff, bf16_t* dst, int R, int C) {
            J.s32[nj] = (const void*)((const float*) d_in[idx] + eoff);
            J.s16[nj] = (const void*)((const bf16_t*)d_in[idx] + eoff);
            J.dst[nj] = dst; J.R[nj] = R; J.C[nj] = C;
            J.pfx[nj] = acc;
            acc += (C / 32) * (R / 32);
            ++nj;
        };
        for (int l = 0; l < LY; ++l) {
            add(8,  (size_t)l * 256 * 1024, cw1T + (size_t)l * 1024 * 256, 256, 1024);
            add(12, (size_t)l * 1024 * 256, cw2T + (size_t)l * 256 * 1024, 1024, 256);
        }
        for (int l = 0; l < LY - 1; ++l) {
            add(16, (size_t)l * 256 * 1024, vw1T + (size_t)l * 1024 * 256, 256, 1024);
            add(20, (size_t)l * 1024 * 256, vw2T + (size_t)l * 256 * 1024, 1024, 256);
        }
        add(22, 0, pw1T, 256, 256);
        add(26, 0, pw2T, 256, 256);
        J.pfx[nj] = acc;
        J.njobs = nj;
        k_tp_all<<<acc, 256, 0, stream>>>(J, dflag);
    }

    k_init_h<<<NN, 256, 0, stream>>>(xi, atomA, h);
    k_init_vn<<<GG, 256, 0, stream>>>(vneA, vn);
    k_zero_cnt<<<(NN + 255) / 256, 256, 0, stream>>>(cnt);
    k_bucket<<<(EE + 255) / 256, 256, 0, stream>>>(ei, ea, cnt, slots);

    for (int l = 0; l < LY; ++l) {
        const int has_vn = (l < LY - 1) ? 1 : 0;
        k_addvn_segmax<<<GG, 128, 0, stream>>>(h, vn, vpb, has_vn);
        k_gather<<<NN, 128, 0, stream>>>(h, bondA + (size_t)l * 5 * H,
                                         cnt, slots, epsA, l, Xb);
        const int lv = (l < LY - 1) ? l : 0;
        k_mlp_dual<<<NBLK_NODE + (has_vn ? NBLK_VN : 0), 1024, 0, stream>>>(
            Xb, vpb,
            cw1T + (size_t)l * 1024 * 256, vw1T + (size_t)lv * 1024 * 256,
            cb1A + (size_t)l * 1024,       vb1A + (size_t)lv * 1024,
            clngA + (size_t)l * 1024,      vlngA + (size_t)lv * 1024,
            clnbA + (size_t)l * 1024,      vlnbA + (size_t)lv * 1024,
            cw2T + (size_t)l * 256 * 1024, vw2T + (size_t)lv * 256 * 1024,
            cb2A + (size_t)l * 256,        vb2A + (size_t)lv * 256,
            ngA + (size_t)l * H, nbA + (size_t)l * H,
            h, vn, has_vn, NBLK_NODE, has_vn);
    }

    k_graphsum<<<GG, 128, 0, stream>>>(h, hgb);
    k_mlp_proj<<<GG / 32, 512, 0, stream>>>(hgb, pw1T, pb1A, plngA, plnbA, pw2T, pb2A, pout2);
    k_norm<<<GG, 256, 0, stream>>>(pout2, outz);
}

// Round 5
// 3962.680 us; speedup vs baseline: 2.1574x; 1.1684x over previous
//
#include <hip/hip_runtime.h>
#include <math.h>

typedef __bf16 bf16_t;
typedef __bf16 bfrag  __attribute__((ext_vector_type(8)));  // 8 bf16 (MFMA A/B frag)
typedef __bf16 b4     __attribute__((ext_vector_type(4)));  // 4 bf16 = 8B vector store
typedef __bf16 b2v    __attribute__((ext_vector_type(2)));  // 2 bf16 = 4B vector
typedef float  f32x4  __attribute__((ext_vector_type(4)));  // MFMA C/D frag

static constexpr int LY  = 5;
static constexpr int H   = 256;
static constexpr int NN  = 200000;
static constexpr int EE  = 400000;
static constexpr int GG  = 8000;
static constexpr int NPG = 25;
static constexpr int CAP = 24;   // max buffered in-edges/node (Poisson(2): P(>24) ~ 1e-17)
static constexpr int NBLK_NODE = NN / 32;   // 6250
static constexpr int NBLK_VN   = GG / 32;   // 250

// tanh-approx GELU (~8 VALU ops; |delta| vs exact erf-gelu ~3e-4 absolute)
__device__ __forceinline__ float gelu_f(float x) {
    const float y = 0.7978845608028654f * x * (1.0f + 0.044715f * x * x);
    const float e = __expf(2.0f * y);
    const float t = 1.0f - 2.0f / (e + 1.0f);
    return 0.5f * x * (1.0f + t);
}

// ---- barrier helpers: NO vm-drain barriers (counted vmcnt) ----
// lgkm_bar: orders LDS reads/writes across the block; leaves global_load_lds
// prefetches in flight.
__device__ __forceinline__ void lgkm_bar() {
    asm volatile("s_waitcnt lgkmcnt(0)" ::: "memory");
    __builtin_amdgcn_sched_barrier(0);
    __builtin_amdgcn_s_barrier();
    __builtin_amdgcn_sched_barrier(0);
}
// vm_bar<N>: wait own vmcnt<=N then barrier (all waves' unit-u loads landed).
template <int N>
__device__ __forceinline__ void vm_bar() {
    if constexpr (N == 0) asm volatile("s_waitcnt vmcnt(0)" ::: "memory");
    else                  asm volatile("s_waitcnt vmcnt(1)" ::: "memory");
    __builtin_amdgcn_sched_barrier(0);
    __builtin_amdgcn_s_barrier();
    __builtin_amdgcn_sched_barrier(0);
}

// ---------------- diagnostics ----------------
__global__ void k_fill(float* __restrict__ out, float v, int n) {
    const int i = blockIdx.x * 256 + threadIdx.x;
    if (i < n) out[i] = v;
}

// ---------------- dtype detection ----------------
__global__ void k_detect(const void* __restrict__ probe, int* __restrict__ flag) {
    const bf16_t* p = (const bf16_t*)probe;
    int bad = 0;
    for (int i = threadIdx.x; i < 256; i += 64) {
        const float v = (float)p[i];
        if (!(v == v) || fabsf(v) > 1000.0f) bad = 1;
    }
    const int any = __any(bad) ? 1 : 0;
    if (threadIdx.x == 0) *flag = any;
}

// ---------------- batched param conversion (1 launch) ----------------
struct CvtJobs {
    const void* src[18];
    bf16_t*     dst[18];
    int         pfx[19];
    int         njobs;
};
__global__ void k_cvt_all(CvtJobs J, const int* __restrict__ flag) {
    const int i = blockIdx.x * 256 + threadIdx.x;
    if (i >= J.pfx[J.njobs]) return;
    int j = 0;
    while (i >= J.pfx[j + 1]) ++j;
    const int loc = i - J.pfx[j];
    if (*flag) J.dst[j][loc] = (bf16_t)((const float*)J.src[j])[loc];
    else       J.dst[j][loc] = ((const bf16_t*)J.src[j])[loc];
}

// ---------------- batched weight transpose (1 launch) ----------------
struct TpJobs {
    const void* s32[22];
    const void* s16[22];
    bf16_t*     dst[22];
    int R[22], C[22];
    int pfx[23];
    int njobs;
};
__global__ void k_tp_all(TpJobs J, const int* __restrict__ flag) {
    __shared__ bf16_t t[32][33];
    const int tile = blockIdx.x;
    int j = 0;
    while (tile >= J.pfx[j + 1]) ++j;
    const int tl = tile - J.pfx[j];
    const int C = J.C[j], R = J.R[j];
    const int ntx = C / 32;
    const int c0 = (tl % ntx) * 32, r0 = (tl / ntx) * 32;
    const int f = *flag;
    const int tx = threadIdx.x & 31, ty = threadIdx.x >> 5;
    #pragma unroll
    for (int i = 0; i < 4; ++i) {
        const int r = ty + i * 8;
        const size_t idx = (size_t)(r0 + r) * C + c0 + tx;
        t[r][tx] = f ? (bf16_t)((const float*)J.s32[j])[idx] : ((const bf16_t*)J.s16[j])[idx];
    }
    __syncthreads();
    #pragma unroll
    for (int i = 0; i < 4; ++i) {
        const int r = ty + i * 8;
        J.dst[j][(size_t)(c0 + r) * R + r0 + tx] = t[tx][r];
    }
}

// ---------------- init ----------------
__global__ void k_init_h(const int* __restrict__ x, const bf16_t* __restrict__ atom,
                         bf16_t* __restrict__ h) {
    const size_t idx = (size_t)blockIdx.x * 256 + threadIdx.x;
    const int row = (int)(idx >> 8), col = (int)(idx & 255);
    h[idx] = atom[(size_t)x[row] * H + col];
}

__global__ void k_init_vn(const bf16_t* __restrict__ vne, float* __restrict__ vn) {
    const size_t idx = (size_t)blockIdx.x * 256 + threadIdx.x;
    vn[idx] = (float)vne[idx & 255];
}

// ---------------- edge bucket build (packed src|attr slots) ----------------
__global__ void k_zero_cnt(int* __restrict__ cnt) {
    const int i = blockIdx.x * 256 + threadIdx.x;
    if (i < NN) cnt[i] = 0;
}

// slots hold src | (attr << 18)  (src < 2^18 since NN=200000 < 262144; attr < 8)
__global__ void k_bucket(const int* __restrict__ ei, const int* __restrict__ ea,
                         int* __restrict__ cnt, int* __restrict__ slots) {
    const int e = blockIdx.x * 256 + threadIdx.x;
    if (e >= EE) return;
    const int d = ei[EE + e];
    const int s = ei[e];
    const int a = ea[e];
    const int slot = atomicAdd(&cnt[d], 1);
    if (slot < CAP) slots[(size_t)d * CAP + slot] = s | (a << 18);
}

// ---------------- fused addvn + segment_max (block = 1 graph, bf16x2 lanes) ----------------
__global__ void k_addvn_segmax(bf16_t* __restrict__ h, const float* __restrict__ vn,
                               bf16_t* __restrict__ vp, int do_max) {
    const int g = blockIdx.x, t = threadIdx.x;   // 128 threads; cols 2t, 2t+1
    const float2 v = *(const float2*)(vn + (size_t)g * H + 2 * t);
    float mx0 = -1e30f, mx1 = -1e30f;
    #pragma unroll 5
    for (int i = 0; i < NPG; ++i) {
        bf16_t* p = h + ((size_t)g * NPG + i) * H + 2 * t;
        const b2v hv = *(const b2v*)p;
        const float h0 = (float)hv[0] + v.x;
        const float h1 = (float)hv[1] + v.y;
        b2v o; o[0] = (bf16_t)h0; o[1] = (bf16_t)h1;
        *(b2v*)p = o;
        mx0 = fmaxf(mx0, h0); mx1 = fmaxf(mx1, h1);
    }
    if (do_max) {
        b2v o; o[0] = (bf16_t)mx0; o[1] = (bf16_t)mx1;
        *(b2v*)(vp + (size_t)g * H + 2 * t) = o;
    }
}

// ---------------- edge gather (bf16x2 lanes; packed slots: 2-level chain) ----------------
__global__ void k_gather(const bf16_t* __restrict__ h,
                         const bf16_t* __restrict__ bondl,
                         const int* __restrict__ cnt, const int* __restrict__ slots,
                         const bf16_t* __restrict__ epsb, int l, bf16_t* __restrict__ Xb) {
    const int n = blockIdx.x, t = threadIdx.x;   // 128 threads; cols 2t, 2t+1
    int deg = cnt[n];
    if (deg > CAP) deg = CAP;
    float m0 = 0.0f, m1 = 0.0f;
    for (int i = 0; i < deg; ++i) {
        const int p = slots[(size_t)n * CAP + i];
        const int s = p & 0x3FFFF;
        const int a = p >> 18;
        const b2v hv = *(const b2v*)(h + (size_t)s * H + 2 * t);
        const b2v bv = *(const b2v*)(bondl + (size_t)a * H + 2 * t);
        m0 += gelu_f((float)hv[0] + (float)bv[0]);
        m1 += gelu_f((float)hv[1] + (float)bv[1]);
    }
    const float eps1 = 1.0f + (float)epsb[l];
    const b2v hn = *(const b2v*)(h + (size_t)n * H + 2 * t);
    b2v o;
    o[0] = (bf16_t)(eps1 * (float)hn[0] + m0);
    o[1] = (bf16_t)(eps1 * (float)hn[1] + m1);
    *(b2v*)(Xb + (size_t)n * H + 2 * t) = o;
}

__global__ void k_graphsum(const bf16_t* __restrict__ h, bf16_t* __restrict__ hg) {
    const int g = blockIdx.x, t = threadIdx.x;   // 128 threads
    float s0 = 0.0f, s1 = 0.0f;
    #pragma unroll 5
    for (int i = 0; i < NPG; ++i) {
        const b2v hv = *(const b2v*)(h + ((size_t)g * NPG + i) * H + 2 * t);
        s0 += (float)hv[0]; s1 += (float)hv[1];
    }
    b2v o; o[0] = (bf16_t)s0; o[1] = (bf16_t)s1;
    *(b2v*)(hg + (size_t)g * H + 2 * t) = o;
}

__global__ void k_norm(const float* __restrict__ z, float* __restrict__ out) {
    const int row = blockIdx.x, t = threadIdx.x;
    const size_t idx = (size_t)row * H + t;
    const float v = z[idx];
    float q = v * v;
    #pragma unroll
    for (int o = 32; o > 0; o >>= 1) q += __shfl_xor(q, o, 64);
    __shared__ float rq[4];
    const int wave = t >> 6, lane = t & 63;
    if (lane == 0) rq[wave] = q;
    __syncthreads();
    q = rq[0] + rq[1] + rq[2] + rq[3];
    out[idx] = v * rsqrtf(q);
}

// ---------------- fused MLP dual: node (LN+res) + vn (accumulate) in ONE dispatch ----------------
// Round-0 geometry (M=32, 512 thr, hid 64 KB, slab 16 KB, 80 KB LDS, 2 blk/CU)
// with the per-round vmcnt(0) drain removed: the 16 KB slab is split into
// 2 x 8 KB units (128 cols x 32 k), staged ahead-1 with counted s_waitcnt
// vmcnt(1) (never 0 mid-loop) and drain-free raw s_barriers:
//   unit u: [lgkmcnt(0);bar][stage u+1][vmcnt(1);bar][2 MFMAs]
// WAR safety (2 buffers, ahead-1, double bar): stage u+1 targets buf[(u+1)&1],
// last read at unit u-1; the first bar follows compute u-1 on all waves.
// 128 units span GEMM1(64)+GEMM2(64) as ONE pipeline; W2's first unit issues
// at GEMM1's last unit and rides through the LN phase (lgkm-only barriers).
// Slab swizzle moved to the global SOURCE (j^(col&3)) with linear LDS dest;
// reads use the same XOR (both-sides rule). Biases preloaded so no stray
// global loads perturb the vm counter.
__launch_bounds__(512, 4)
__global__ void k_mlp_dual(const bf16_t* __restrict__ Xn, const bf16_t* __restrict__ Xv,
                           const bf16_t* __restrict__ nW1T, const bf16_t* __restrict__ vW1T,
                           const bf16_t* __restrict__ nb1, const bf16_t* __restrict__ vb1,
                           const bf16_t* __restrict__ nlng, const bf16_t* __restrict__ vlng,
                           const bf16_t* __restrict__ nlnb, const bf16_t* __restrict__ vlnb,
                           const bf16_t* __restrict__ nW2T, const bf16_t* __restrict__ vW2T,
                           const bf16_t* __restrict__ nb2, const bf16_t* __restrict__ vb2,
                           const bf16_t* __restrict__ g2, const bf16_t* __restrict__ b2ln,
                           bf16_t* __restrict__ hres, float* __restrict__ vnacc,
                           int gelu_flag, int nblk_node, int has_vn) {
    constexpr int HID = 1024;
    __shared__ __align__(16) bf16_t hid[32 * HID];  // 64 KB
    __shared__ __align__(16) bf16_t wbuf[8192];     // 16 KB = 2 x 8 KB units
    const int tid  = threadIdx.x;
    const int lane = tid & 63, wave = tid >> 6;
    const int c16  = lane & 15, quad = lane >> 4;

    const bool is_node = (int)blockIdx.x < nblk_node;
    const size_t rowblk = is_node ? (size_t)blockIdx.x * 32
                                  : (size_t)((int)blockIdx.x - nblk_node) * 32;
    const bf16_t* X    = is_node ? Xn   : Xv;
    const bf16_t* W1T  = is_node ? nW1T : vW1T;
    const bf16_t* W2T  = is_node ? nW2T : vW2T;
    const bf16_t* b1   = is_node ? nb1  : vb1;
    const bf16_t* lng  = is_node ? nlng : vlng;
    const bf16_t* lnb  = is_node ? nlnb : vlnb;
    const bf16_t* b2   = is_node ? nb2  : vb2;

    // units 0..63: W1 (c=u>>3, kc=(u>>1)&3, s=u&1); 64..127: W2 (cp, kk).
    // unit = 128 cols x 32 k = 8 KB; 512 threads x 16 B; slot f: col=f>>2, j=f&3.
    // content at (col,j) = W[col][k0 + (j^(col&3))*8]  (source-side XOR).
    auto stage_unit = [&](int u) {
        const int f   = wave * 64 + lane;          // 0..511
        const int col = f >> 2, j = f & 3;
        const bf16_t* gp;
        if (u < 64) {
            const int cps = u >> 3, kc = (u >> 1) & 3, s = u & 1;
            gp = W1T + (size_t)(cps * 128 + col) * 256 + kc * 64 + s * 32
                     + ((j ^ (col & 3)) * 8);
        } else {
            const int u2 = u - 64, cp = u2 >> 5, kk = u2 & 31;
            gp = W2T + (size_t)(cp * 128 + col) * 1024 + kk * 32
                     + ((j ^ (col & 3)) * 8);
        }
        bf16_t* lp = wbuf + (u & 1) * 4096 + wave * 512;   // wave-uniform base
        __builtin_amdgcn_global_load_lds(
            (const __attribute__((address_space(1))) void*)gp,
            (__attribute__((address_space(3))) void*)lp, 16, 0, 0);
    };
    // read frag: (crel, quad) -> W[crel][k0 + quad*8 .. +8]
    auto wfrag8 = [&](const bf16_t* sb, int crel) -> bfrag {
        return *(const bfrag*)(sb + crel * 32 + ((quad ^ (crel & 3)) * 8));
    };

    // ---- bias preload (keeps vm counter clean inside loops) ----
    b4 bias1[8], bias2[2];
    #pragma unroll
    for (int c = 0; c < 8; ++c)
        bias1[c] = *(const b4*)(b1 + c * 128 + wave * 16 + quad * 4);
    #pragma unroll
    for (int cp = 0; cp < 2; ++cp)
        bias2[cp] = *(const b4*)(b2 + cp * 128 + wave * 16 + quad * 4);

    // ---- X a-frags (read once) ----
    const bf16_t* xr0 = X + (rowblk + c16) * 256 + quad * 8;
    const bf16_t* xr1 = X + (rowblk + 16 + c16) * 256 + quad * 8;
    bfrag xa[8][2];
    #pragma unroll
    for (int ks = 0; ks < 8; ++ks) {
        xa[ks][0] = *(const bfrag*)(xr0 + ks * 32);
        xa[ks][1] = *(const bfrag*)(xr1 + ks * 32);
    }

    // ---- pipeline prologue ----
    stage_unit(0);

    // ---- GEMM1: hid[32,1024] = X[32,256] @ W1 ----
    #pragma unroll
    for (int c = 0; c < 8; ++c) {
        f32x4 acc[2];
        acc[0] = f32x4{0.f, 0.f, 0.f, 0.f};
        acc[1] = f32x4{0.f, 0.f, 0.f, 0.f};
        #pragma unroll
        for (int kc = 0; kc < 4; ++kc) {
            #pragma unroll
            for (int s = 0; s < 2; ++s) {
                const int u = ((c * 4 + kc) << 1) | s;   // 0..63
                lgkm_bar();
                stage_unit(u + 1);                       // u+1 <= 64 (first W2 unit)
                vm_bar<1>();
                const bf16_t* sb = wbuf + (u & 1) * 4096;
                const bfrag w0 = wfrag8(sb, wave * 16 + c16);
                const int ks = kc * 2 + s;
                acc[0] = __builtin_amdgcn_mfma_f32_16x16x32_bf16(w0, xa[ks][0], acc[0], 0, 0, 0);
                acc[1] = __builtin_amdgcn_mfma_f32_16x16x32_bf16(w0, xa[ks][1], acc[1], 0, 0, 0);
            }
        }
        const int kb = c * 128 + wave * 16 + quad * 4;
        #pragma unroll
        for (int mt = 0; mt < 2; ++mt) {
            const int xr = mt * 16 + c16;
            const f32x4 a = mt ? acc[1] : acc[0];
            b4 o;
            #pragma unroll
            for (int r = 0; r < 4; ++r)
                o[r] = (bf16_t)(a[r] + (float)bias1[c][r]);
            const int ch = ((kb >> 3) ^ (xr & 7));
            *(b4*)(hid + xr * HID + ch * 8 + (kb & 7)) = o;
        }
    }
    lgkm_bar();   // hid visible; W2 unit-64 prefetch stays in flight

    // ---- LN(1024) + GELU in LDS: 16 threads/row ----
    {
        const int row = tid >> 4, p = tid & 15;
        float sum = 0.f, ss = 0.f;
        #pragma unroll
        for (int i = 0; i < HID / 128; ++i) {
            const int j0 = p * 8 + i * 128;
            const int ch = ((j0 >> 3) ^ (row & 7));
            bfrag v = *(const bfrag*)(hid + row * HID + ch * 8);
            #pragma unroll
            for (int k = 0; k < 8; ++k) { const float f = (float)v[k]; sum += f; ss += f * f; }
        }
        #pragma unroll
        for (int o = 1; o < 16; o <<= 1) { sum += __shfl_xor(sum, o, 64); ss += __shfl_xor(ss, o, 64); }
        const float mean = sum * (1.0f / HID);
        const float var  = ss * (1.0f / HID) - mean * mean;
        const float rinv = rsqrtf(var + 1e-5f);
        #pragma unroll
        for (int i = 0; i < HID / 128; ++i) {
            const int j0 = p * 8 + i * 128;
            const int ch = ((j0 >> 3) ^ (row & 7));
            bfrag v  = *(const bfrag*)(hid + row * HID + ch * 8);
            bfrag gv = *(const bfrag*)(lng + j0);
            bfrag bv = *(const bfrag*)(lnb + j0);
            bfrag o8;
            #pragma unroll
            for (int k = 0; k < 8; ++k) {
                const float f = ((float)v[k] - mean) * rinv * (float)gv[k] + (float)bv[k];
                o8[k] = (bf16_t)gelu_f(f);
            }
            *(bfrag*)(hid + row * HID + ch * 8) = o8;
        }
    }
    lgkm_bar();   // LN writes visible; prefetch still in flight

    // ---- GEMM2: res[32,256] = hid[32,1024] @ W2 ----
    {
        f32x4 acc2[2][2];   // [colpass][mt]
        #pragma unroll
        for (int cp = 0; cp < 2; ++cp)
            #pragma unroll
            for (int mt = 0; mt < 2; ++mt)
                acc2[cp][mt] = f32x4{0.f, 0.f, 0.f, 0.f};
        #pragma unroll
        for (int cp = 0; cp < 2; ++cp) {
            #pragma unroll
            for (int kk = 0; kk < 32; ++kk) {
                const int u = 64 + cp * 32 + kk;   // 64..127
                lgkm_bar();
                if (u < 127) { stage_unit(u + 1); vm_bar<1>(); }
                else         { vm_bar<0>(); }
                const bf16_t* sb = wbuf + (u & 1) * 4096;
                const bfrag w0 = wfrag8(sb, wave * 16 + c16);
                const int k = kk * 32 + quad * 8;
                bfrag hb[2];
                #pragma unroll
                for (int mt = 0; mt < 2; ++mt) {
                    const int row = mt * 16 + c16;
                    const int ch = ((k >> 3) ^ (row & 7));
                    hb[mt] = *(const bfrag*)(hid + row * HID + ch * 8);
                }
                acc2[cp][0] = __builtin_amdgcn_mfma_f32_16x16x32_bf16(w0, hb[0], acc2[cp][0], 0, 0, 0);
                acc2[cp][1] = __builtin_amdgcn_mfma_f32_16x16x32_bf16(w0, hb[1], acc2[cp][1], 0, 0, 0);
            }
        }

        if (!is_node) {
            if (has_vn) {
                #pragma unroll
                for (int cp = 0; cp < 2; ++cp)
                    #pragma unroll
                    for (int mt = 0; mt < 2; ++mt) {
                        const int cb = cp * 128 + wave * 16 + quad * 4;
                        float* po = vnacc + (rowblk + mt * 16 + c16) * 256 + cb;
                        const f32x4 old = *(const f32x4*)po;
                        f32x4 v;
                        #pragma unroll
                        for (int r = 0; r < 4; ++r) v[r] = old[r] + acc2[cp][mt][r] + (float)bias2[cp][r];
                        *(f32x4*)po = v;
                    }
            }
        } else {
            constexpr int OS = 260;
            float* ot = (float*)hid;
            __syncthreads();
            #pragma unroll
            for (int cp = 0; cp < 2; ++cp)
                #pragma unroll
                for (int mt = 0; mt < 2; ++mt) {
                    const int cb = cp * 128 + wave * 16 + quad * 4;
                    f32x4 v;
                    #pragma unroll
                    for (int r = 0; r < 4; ++r) v[r] = acc2[cp][mt][r] + (float)bias2[cp][r];
                    *(f32x4*)(ot + (mt * 16 + c16) * OS + cb) = v;
                }
            __syncthreads();
            const int row = tid >> 4, p = tid & 15;
            float s = 0.f, q = 0.f;
            #pragma unroll
            for (int i = 0; i < 16; ++i) {
                const float f = ot[row * OS + p + 16 * i];
                s += f; q += f * f;
            }
            #pragma unroll
            for (int o = 1; o < 16; o <<= 1) { s += __shfl_xor(s, o, 64); q += __shfl_xor(q, o, 64); }
            const float mean = s * (1.0f / 256.0f);
            const float var  = q * (1.0f / 256.0f) - mean * mean;
            const float rinv = rsqrtf(var + 1e-5f);
            const size_t rg = (rowblk + row) * 256;
            #pragma unroll
            for (int i = 0; i < 2; ++i) {
                const int j0 = p * 16 + i * 8;
                bfrag gv = *(const bfrag*)(g2 + j0);
                bfrag bv = *(const bfrag*)(b2ln + j0);
                bfrag hv = *(const bfrag*)(hres + rg + j0);
                bfrag o8;
                #pragma unroll
                for (int k = 0; k < 8; ++k) {
                    float f = (ot[row * OS + j0 + k] - mean) * rinv * (float)gv[k] + (float)bv[k];
                    if (gelu_flag) f = gelu_f(f);
                    o8[k] = (bf16_t)(f + (float)hv[k]);
                }
                *(bfrag*)(hres + rg + j0) = o8;
            }
        }
    }
}

// ---------------- small MLP (final projection, HID=256) ----------------
__launch_bounds__(512, 4)
__global__ void k_mlp_proj(const bf16_t* __restrict__ X, const bf16_t* __restrict__ W1T,
                           const bf16_t* __restrict__ b1, const bf16_t* __restrict__ lng,
                           const bf16_t* __restrict__ lnb, const bf16_t* __restrict__ W2T,
                           const bf16_t* __restrict__ b2, float* __restrict__ outf) {
    constexpr int HID = 256;
    constexpr int NP1 = HID / 128;   // 2
    constexpr int NQ2 = HID / 64;    // 4
    __shared__ bf16_t hid[32 * HID];
    __shared__ bf16_t wbuf[8192];
    const int tid  = threadIdx.x;
    const int lane = tid & 63, wave = tid >> 6;
    const int c16  = lane & 15, quad = lane >> 4;
    const size_t rowblk = (size_t)blockIdx.x * 32;

    auto stage = [&](const bf16_t* WT, int KW, int colbase, int k0) {
        #pragma unroll
        for (int j = 0; j < 2; ++j) {
            const int grp    = wave * 2 + j;
            const int colrel = grp * 8 + (lane >> 3);
            const int slot   = lane & 7;
            const int kq     = slot ^ (colrel & 7);
            const bf16_t* gp = WT + (size_t)(colbase + colrel) * KW + k0 + kq * 8;
            bf16_t* lp = &wbuf[(size_t)grp * 512];
            __builtin_amdgcn_global_load_lds(
                (const __attribute__((address_space(1))) void*)gp,
                (__attribute__((address_space(3))) void*)lp, 16, 0, 0);
        }
    };
    auto wfrag = [&](int crel, int g) -> bfrag {
        return *(const bfrag*)(wbuf + crel * 64 + ((g ^ (crel & 7)) * 8));
    };

    const bf16_t* xr0 = X + (rowblk + c16) * 256 + quad * 8;
    const bf16_t* xr1 = X + (rowblk + 16 + c16) * 256 + quad * 8;
    bfrag xa[8][2];
    #pragma unroll
    for (int ks = 0; ks < 8; ++ks) {
        xa[ks][0] = *(const bfrag*)(xr0 + ks * 32);
        xa[ks][1] = *(const bfrag*)(xr1 + ks * 32);
    }

    #pragma unroll
    for (int c = 0; c < NP1; ++c) {
        const int nbase = c * 128 + wave * 16;
        f32x4 acc[2];
        acc[0] = f32x4{0.f, 0.f, 0.f, 0.f};
        acc[1] = f32x4{0.f, 0.f, 0.f, 0.f};
        #pragma unroll
        for (int kc = 0; kc < 4; ++kc) {
            stage(W1T, 256, c * 128, kc * 64);
            __syncthreads();
            #pragma unroll
            for (int s = 0; s < 2; ++s) {
                const int ks = kc * 2 + s;
                const int g  = s * 4 + quad;
                const bfrag w0 = wfrag(wave * 16 + c16, g);
                #pragma unroll
                for (int mt = 0; mt < 2; ++mt)
                    acc[mt] = __builtin_amdgcn_mfma_f32_16x16x32_bf16(
                        w0, xa[ks][mt], acc[mt], 0, 0, 0);
            }
            __syncthreads();
        }
        #pragma unroll
        for (int mt = 0; mt < 2; ++mt) {
            const int kb = nbase + quad * 4;
            const int xr = mt * 16 + c16;
            const b4 bias = *(const b4*)(b1 + kb);
            b4 o;
            #pragma unroll
            for (int r = 0; r < 4; ++r)
                o[r] = (bf16_t)(acc[mt][r] + (float)bias[r]);
            const int ch = ((kb >> 3) ^ (xr & 7));
            *(b4*)(hid + xr * HID + ch * 8 + (kb & 7)) = o;
        }
    }
    __syncthreads();

    {
        const int row = tid >> 4, p = tid & 15;
        float sum = 0.f, ss = 0.f;
        #pragma unroll
        for (int i = 0; i < HID / 128; ++i) {
            const int j0 = p * 8 + i * 128;
            const int ch = ((j0 >> 3) ^ (row & 7));
            bfrag v = *(const bfrag*)(hid + row * HID + ch * 8);
            #pragma unroll
            for (int k = 0; k < 8; ++k) { const float f = (float)v[k]; sum += f; ss += f * f; }
        }
        #pragma unroll
        for (int o = 1; o < 16; o <<= 1) { sum += __shfl_xor(sum, o, 64); ss += __shfl_xor(ss, o, 64); }
        const float mean = sum * (1.0f / HID);
        const float var  = ss * (1.0f / HID) - mean * mean;
        const float rinv = rsqrtf(var + 1e-5f);
        #pragma unroll
        for (int i = 0; i < HID / 128; ++i) {
            const int j0 = p * 8 + i * 128;
            const int ch = ((j0 >> 3) ^ (row & 7));
            bfrag v  = *(const bfrag*)(hid + row * HID + ch * 8);
            bfrag gv = *(const bfrag*)(lng + j0);
            bfrag bv = *(const bfrag*)(lnb + j0);
            bfrag o8;
            #pragma unroll
            for (int k = 0; k < 8; ++k) {
                const float f = ((float)v[k] - mean) * rinv * (float)gv[k] + (float)bv[k];
                o8[k] = (bf16_t)gelu_f(f);
            }
            *(bfrag*)(hid + row * HID + ch * 8) = o8;
        }
    }
    __syncthreads();

    {
        f32x4 acc2[2][2];
        #pragma unroll
        for (int cp = 0; cp < 2; ++cp)
            #pragma unroll
            for (int mt = 0; mt < 2; ++mt)
                acc2[cp][mt] = f32x4{0.f, 0.f, 0.f, 0.f};
        #pragma unroll
        for (int cp = 0; cp < 2; ++cp) {
            for (int q2 = 0; q2 < NQ2; ++q2) {
                stage(W2T, HID, cp * 128, q2 * 64);
                __syncthreads();
                #pragma unroll
                for (int s = 0; s < 2; ++s) {
                    const int g = s * 4 + quad;
                    const bfrag w0 = wfrag(wave * 16 + c16, g);
                    const int k = q2 * 64 + s * 32 + quad * 8;
                    bfrag hb[2];
                    #pragma unroll
                    for (int mt = 0; mt < 2; ++mt) {
                        const int row = mt * 16 + c16;
                        const int ch = ((k >> 3) ^ (row & 7));
                        hb[mt] = *(const bfrag*)(hid + row * HID + ch * 8);
                    }
                    #pragma unroll
                    for (int mt = 0; mt < 2; ++mt)
                        acc2[cp][mt] = __builtin_amdgcn_mfma_f32_16x16x32_bf16(
                            w0, hb[mt], acc2[cp][mt], 0, 0, 0);
                }
                __syncthreads();
            }
        }
        #pragma unroll
        for (int cp = 0; cp < 2; ++cp)
            #pragma unroll
            for (int mt = 0; mt < 2; ++mt) {
                const int cb = cp * 128 + wave * 16 + quad * 4;
                const b4 b2vv = *(const b4*)(b2 + cb);
                f32x4 v;
                #pragma unroll
                for (int r = 0; r < 4; ++r) v[r] = acc2[cp][mt][r] + (float)b2vv[r];
                *(f32x4*)(outf + (rowblk + mt * 16 + c16) * 256 + cb) = v;
            }
    }
}

// ---------------- host launch ----------------
extern "C" void kernel_launch(void* const* d_in, const int* in_sizes, int n_in,
                              void* d_out, int out_size, void* d_ws, size_t ws_size,
                              hipStream_t stream) {
    float* outz = (float*)d_out;

    const bool layout_ok =
        (n_in == 28) &&
        in_sizes[0] == 200000 && in_sizes[1] == 800000 &&
        in_sizes[2] == 400000 && in_sizes[3] == 200000 &&
        in_sizes[4] == 118 * 256 && in_sizes[6] == 5 * 5 * 256 &&
        in_sizes[8] == 5 * 256 * 1024 && in_sizes[27] == 256 &&
        out_size == GG * H;
    if (!layout_ok) {
        k_fill<<<(out_size + 255) / 256, 256, 0, stream>>>(outz, 777.0f, out_size);
        return;
    }

    char* w = (char*)d_ws;
    size_t off = 0;
    auto alloc = [&](size_t bytes) -> void* {
        void* p = w + off;
        off += (bytes + 255) & ~(size_t)255;
        return p;
    };
    bf16_t* h     = (bf16_t*)alloc((size_t)NN * H * 2);
    bf16_t* Xb    = (bf16_t*)alloc((size_t)NN * H * 2);
    float*  vn    = (float*) alloc((size_t)GG * H * 4);
    bf16_t* vpb   = (bf16_t*)alloc((size_t)GG * H * 2);
    bf16_t* hgb   = (bf16_t*)alloc((size_t)GG * H * 2);
    float*  pout2 = (float*) alloc((size_t)GG * H * 4);
    int*    cnt   = (int*)   alloc((size_t)NN * 4);
    int*    slots = (int*)   alloc((size_t)NN * CAP * 4);
    int*    dflag = (int*)   alloc(256);
    bf16_t* cw1T  = (bf16_t*)alloc((size_t)LY * 1024 * 256 * 2);
    bf16_t* cw2T  = (bf16_t*)alloc((size_t)LY * 256 * 1024 * 2);
    bf16_t* vw1T  = (bf16_t*)alloc((size_t)(LY - 1) * 1024 * 256 * 2);
    bf16_t* vw2T  = (bf16_t*)alloc((size_t)(LY - 1) * 256 * 1024 * 2);
    bf16_t* pw1T  = (bf16_t*)alloc((size_t)256 * 256 * 2);
    bf16_t* pw2T  = (bf16_t*)alloc((size_t)256 * 256 * 2);
    bf16_t* atomA = (bf16_t*)alloc((size_t)118 * 256 * 2);
    bf16_t* vneA  = (bf16_t*)alloc(256 * 2);
    bf16_t* bondA = (bf16_t*)alloc((size_t)LY * 5 * 256 * 2);
    bf16_t* epsA  = (bf16_t*)alloc(16 * 2);
    bf16_t* cb1A  = (bf16_t*)alloc((size_t)LY * 1024 * 2);
    bf16_t* clngA = (bf16_t*)alloc((size_t)LY * 1024 * 2);
    bf16_t* clnbA = (bf16_t*)alloc((size_t)LY * 1024 * 2);
    bf16_t* cb2A  = (bf16_t*)alloc((size_t)LY * 256 * 2);
    bf16_t* ngA   = (bf16_t*)alloc((size_t)LY * 256 * 2);
    bf16_t* nbA   = (bf16_t*)alloc((size_t)LY * 256 * 2);
    bf16_t* vb1A  = (bf16_t*)alloc((size_t)(LY - 1) * 1024 * 2);
    bf16_t* vlngA = (bf16_t*)alloc((size_t)(LY - 1) * 1024 * 2);
    bf16_t* vlnbA = (bf16_t*)alloc((size_t)(LY - 1) * 1024 * 2);
    bf16_t* vb2A  = (bf16_t*)alloc((size_t)(LY - 1) * 256 * 2);
    bf16_t* pb1A  = (bf16_t*)alloc(256 * 2);
    bf16_t* plngA = (bf16_t*)alloc(256 * 2);
    bf16_t* plnbA = (bf16_t*)alloc(256 * 2);
    bf16_t* pb2A  = (bf16_t*)alloc(256 * 2);
    if (off > ws_size) {
        k_fill<<<(out_size + 255) / 256, 256, 0, stream>>>(outz, 333.0f, out_size);
        return;
    }

    const int* xi  = (const int*)d_in[0];
    const int* ei  = (const int*)d_in[1];
    const int* ea  = (const int*)d_in[2];

    k_detect<<<1, 64, 0, stream>>>(d_in[8], dflag);

    {
        CvtJobs J{};
        struct { int idx; bf16_t* dst; int n; } cj[18] = {
            {4, atomA, 118 * 256}, {5, vneA, 256}, {6, bondA, LY * 5 * 256}, {7, epsA, LY},
            {9, cb1A, LY * 1024}, {10, clngA, LY * 1024}, {11, clnbA, LY * 1024},
            {13, cb2A, LY * 256}, {14, ngA, LY * 256}, {15, nbA, LY * 256},
            {17, vb1A, (LY - 1) * 1024}, {18, vlngA, (LY - 1) * 1024},
            {19, vlnbA, (LY - 1) * 1024}, {21, vb2A, (LY - 1) * 256},
            {23, pb1A, 256}, {24, plngA, 256}, {25, plnbA, 256}, {27, pb2A, 256},
        };
        int acc = 0;
        J.njobs = 18;
        for (int j = 0; j < 18; ++j) {
            J.src[j] = d_in[cj[j].idx];
            J.dst[j] = cj[j].dst;
            J.pfx[j] = acc;
            acc += cj[j].n;
        }
        J.pfx[18] = acc;
        k_cvt_all<<<(acc + 255) / 256, 256, 0, stream>>>(J, dflag);
    }

    {
        TpJobs J{};
        int nj = 0, acc = 0;
        auto add = [&](int idx, size_t eoff, bf16_t* dst, int R, int C) {
            J.s32[nj] = (const void*)((const float*) d_in[idx] + eoff);
            J.s16[nj] = (const void*)((const bf16_t*)d_in[idx] + eoff);
            J.dst[nj] = dst; J.R[nj] = R; J.C[nj] = C;
            J.pfx[nj] = acc;
            acc += (C / 32) * (R / 32);
            ++nj;
        };
        for (int l = 0; l < LY; ++l) {
            add(8,  (size_t)l * 256 * 1024, cw1T + (size_t)l * 1024 * 256, 256, 1024);
            add(12, (size_t)l * 1024 * 256, cw2T + (size_t)l * 256 * 1024, 1024, 256);
        }
        for (int l = 0; l < LY - 1; ++l) {
            add(16, (size_t)l * 256 * 1024, vw1T + (size_t)l * 1024 * 256, 256, 1024);
            add(20, (size_t)l * 1024 * 256, vw2T + (size_t)l * 256 * 1024, 1024, 256);
        }
        add(22, 0, pw1T, 256, 256);
        add(26, 0, pw2T, 256, 256);
        J.pfx[nj] = acc;
        J.njobs = nj;
        k_tp_all<<<acc, 256, 0, stream>>>(J, dflag);
    }

    k_init_h<<<NN, 256, 0, stream>>>(xi, atomA, h);
    k_init_vn<<<GG, 256, 0, stream>>>(vneA, vn);
    k_zero_cnt<<<(NN + 255) / 256, 256, 0, stream>>>(cnt);
    k_bucket<<<(EE + 255) / 256, 256, 0, stream>>>(ei, ea, cnt, slots);

    for (int l = 0; l < LY; ++l) {
        const int has_vn = (l < LY - 1) ? 1 : 0;
        k_addvn_segmax<<<GG, 128, 0, stream>>>(h, vn, vpb, has_vn);
        k_gather<<<NN, 128, 0, stream>>>(h, bondA + (size_t)l * 5 * H,
                                         cnt, slots, epsA, l, Xb);
        const int lv = (l < LY - 1) ? l : 0;
        k_mlp_dual<<<NBLK_NODE + (has_vn ? NBLK_VN : 0), 512, 0, stream>>>(
            Xb, vpb,
            cw1T + (size_t)l * 1024 * 256, vw1T + (size_t)lv * 1024 * 256,
            cb1A + (size_t)l * 1024,       vb1A + (size_t)lv * 1024,
            clngA + (size_t)l * 1024,      vlngA + (size_t)lv * 1024,
            clnbA + (size_t)l * 1024,      vlnbA + (size_t)lv * 1024,
            cw2T + (size_t)l * 256 * 1024, vw2T + (size_t)lv * 256 * 1024,
            cb2A + (size_t)l * 256,        vb2A + (size_t)lv * 256,
            ngA + (size_t)l * H, nbA + (size_t)l * H,
            h, vn, has_vn, NBLK_NODE, has_vn);
    }

    k_graphsum<<<GG, 128, 0, stream>>>(h, hgb);
    k_mlp_proj<<<GG / 32, 512, 0, stream>>>(hgb, pw1T, pb1A, plngA, plnbA, pw2T, pb2A, pout2);
    k_norm<<<GG, 256, 0, stream>>>(pout2, outz);
}